// Round 13
// baseline (516.599 us; speedup 1.0000x reference)
//
#include <hip/hip_runtime.h>
#include <math.h>

// Problem constants
constexpr int kN  = 50000;     // nodes
constexpr int kE  = 600000;    // raw edges
constexpr int kET = 650000;    // edges + self loops
constexpr int kG  = 50;        // graphs
constexpr int kH  = 4;         // heads
constexpr int kRep = 16;       // BN atomic replicas

// ws layout (float-slot offsets)
constexpr size_t OFF_HCUR   = 0;           // N*64 bf16
constexpr size_t OFF_HNEXT  = 1600000;     // N*64 f32
constexpr size_t OFF_ES     = 11200000;    // N*4 f32
constexpr size_t OFF_ED     = 11400000;    // N*4 f32
constexpr size_t OFF_ROWPTR = 14200000;    // (N+1) ints
constexpr size_t OFF_SRC    = 14320000;    // ET ints
constexpr size_t OFF_WT2    = 14970000;    // 3 x 16384 bf16
constexpr size_t OFF_AHAT   = 15000000;    // 3 x 512 f32
constexpr size_t OFF_SPART  = 15002000;    // 64 ints
// ---- contiguous zero-init region (single memset) ----
constexpr size_t OFF_CURSOR = 15010000;    // N ints
constexpr size_t OFF_BNREP  = 15060000;    // 3 x kRep x 128 f32 = 6144
constexpr size_t OFF_GPOOL  = 15066144;    // gsum[1600] + gmaxe[1600]
constexpr size_t kZeroEnd   = 15069344;

constexpr int kScanBlocks = (kN + 1023) / 1024;   // 49
constexpr int kHistBlocks = (kET + 255) / 256;    // 2540
constexpr int kPrepBlocks = 163;
constexpr int kEncBlocks  = kN / 4;               // 12500
constexpr int kSctBlocks  = (kE / 4 + 255) / 256; // 586 (4 raw edges/thread)
constexpr int kLoopBlocks = (kN + 255) / 256;     // 196 (self-loop direct placement)

typedef __bf16 bf16x8 __attribute__((ext_vector_type(8)));
typedef float  f32x4  __attribute__((ext_vector_type(4)));

__device__ inline ushort f2b(float f) {  // RNE float->bf16 bits
    unsigned u = __float_as_uint(f);
    return (ushort)((u + 0x7FFFu + ((u >> 16) & 1u)) >> 16);
}
__device__ inline float b2f(ushort u) {
    return __uint_as_float(((unsigned)u) << 16);
}
__device__ inline unsigned enc_f(float f) {  // monotone float->uint
    unsigned b = __float_as_uint(f);
    return (b & 0x80000000u) ? ~b : (b | 0x80000000u);
}
__device__ inline float dec_f(unsigned u) {
    return __uint_as_float((u & 0x80000000u) ? (u & 0x7FFFFFFFu) : ~u);
}

__device__ inline void edge_pair(const int* __restrict__ ei, int e, int& src, int& dst) {
    if (e < kE) { src = ei[e]; dst = ei[kE + e]; }
    else        { src = e - kE; dst = e - kE; }
}

// ---------------- fused: weight prep (blocks 0..162) + dst histogram ----------------
__global__ void k_histprep(const int* __restrict__ ei, int* __restrict__ counts,
                           const float* __restrict__ w0, const float* __restrict__ w1,
                           const float* __restrict__ w2, const float* __restrict__ as0,
                           const float* __restrict__ as1, const float* __restrict__ as2,
                           const float* __restrict__ ad0, const float* __restrict__ ad1,
                           const float* __restrict__ ad2, float* __restrict__ ahat,
                           ushort* __restrict__ Wt2) {
    int b = blockIdx.x;
    if (b < 3) {
        const float* W  = (b == 0) ? w0 : (b == 1) ? w1 : w2;
        const float* As = (b == 0) ? as0 : (b == 1) ? as1 : as2;
        const float* Ad = (b == 0) ? ad0 : (b == 1) ? ad1 : ad2;
        int dout = (b == 2) ? 32 : 64;
        int i = threadIdx.x;
        int h = i >> 6, k = i & 63;
        const float* wr = W + (size_t)k * (4 * dout) + h * dout;
        float s1 = 0.f, s2 = 0.f;
        for (int c = 0; c < dout; ++c) {
            float w = wr[c];
            s1 += w * As[h * dout + c];
            s2 += w * Ad[h * dout + c];
        }
        ahat[b * 512 + i] = s1;
        ahat[b * 512 + 256 + i] = s2;
    } else if (b < kPrepBlocks) {
        int i = (b - 3) * 256 + threadIdx.x;   // over 40960
        if (i >= 40960) return;
        int l, li;
        if (i < 16384)      { l = 0; li = i; }
        else if (i < 32768) { l = 1; li = i - 16384; }
        else                { l = 2; li = i - 32768; }
        int dout = (l == 2) ? 32 : 64;
        const float* W = (l == 0) ? w0 : (l == 1) ? w1 : w2;
        int c = li >> 8, kk = li & 255;
        int h = kk >> 6, k = kk & 63;
        Wt2[l * 16384 + li] = f2b(W[(size_t)k * (4 * dout) + h * dout + c]);
    } else {
        int e = (b - kPrepBlocks) * 256 + threadIdx.x;
        if (e >= kET) return;
        int src, dst;
        edge_pair(ei, e, src, dst);
        atomicAdd(&counts[dst], 1);
    }
}

__global__ void __launch_bounds__(1024) k_scan_local(const int* __restrict__ counts,
                                                     int* __restrict__ rowptr,
                                                     int* __restrict__ partials) {
    int tid = threadIdx.x;
    int idx = blockIdx.x * 1024 + tid;
    int val = (idx < kN) ? counts[idx] : 0;
    int lane = tid & 63, w = tid >> 6;
    int x = val;
#pragma unroll
    for (int off = 1; off < 64; off <<= 1) {
        int t = __shfl_up(x, off);
        if (lane >= off) x += t;
    }
    __shared__ int wsum[16];
    if (lane == 63) wsum[w] = x;
    __syncthreads();
    if (w == 0 && lane < 16) {
        int y = wsum[lane];
#pragma unroll
        for (int off = 1; off < 16; off <<= 1) {
            int t = __shfl_up(y, off);
            if (lane >= off) y += t;
        }
        wsum[lane] = y;
    }
    __syncthreads();
    int incl = x + (w > 0 ? wsum[w - 1] : 0);
    if (idx < kN) rowptr[idx + 1] = incl;
    if (tid == 1023) partials[blockIdx.x] = incl;
}

__global__ void k_scan_part(int* __restrict__ partials) {
    int lane = threadIdx.x;
    int v = (lane < kScanBlocks) ? partials[lane] : 0;
    int x = v;
#pragma unroll
    for (int off = 1; off < 64; off <<= 1) {
        int t = __shfl_up(x, off);
        if (lane >= off) x += t;
    }
    if (lane < kScanBlocks) partials[lane] = x - v;
}

__global__ void __launch_bounds__(1024) k_scan_add(int* __restrict__ cursor,
                                                   int* __restrict__ rowptr,
                                                   const int* __restrict__ partials) {
    int idx = blockIdx.x * 1024 + threadIdx.x;
    if (idx >= kN) return;
    int incl = rowptr[idx + 1] + partials[blockIdx.x];
    rowptr[idx + 1] = incl;
    int val = cursor[idx];
    cursor[idx] = incl - val;
    if (idx == 0) rowptr[0] = 0;
}

// ---- fused: encoder+layer0 es/ed | raw-edge scatter (4/thread) | self-loop placement ----
__global__ void __launch_bounds__(256) k_scatter_enc(const int* __restrict__ ei,
                                                     int* __restrict__ cursor,
                                                     int* __restrict__ src_csr,
                                                     const int* __restrict__ rowptr,
                                                     const float* __restrict__ x,
                                                     const float* __restrict__ w,
                                                     const float* __restrict__ b,
                                                     const float* __restrict__ ahat0,
                                                     ushort* __restrict__ h,
                                                     float* __restrict__ es,
                                                     float* __restrict__ ed) {
    if (blockIdx.x < kEncBlocks) {
        int node = blockIdx.x * 4 + (threadIdx.x >> 6);
        int lane = threadIdx.x & 63;
        float acc = b[lane];
#pragma unroll
        for (int k = 0; k < 5; ++k) acc += x[node * 5 + k] * w[k * 64 + lane];
        h[(size_t)node * 64 + lane] = f2b(acc);

        float ps[4], pd[4];
#pragma unroll
        for (int hh = 0; hh < 4; ++hh) {
            ps[hh] = acc * ahat0[hh * 64 + lane];
            pd[hh] = acc * ahat0[256 + hh * 64 + lane];
        }
#pragma unroll
        for (int off = 1; off < 64; off <<= 1) {
#pragma unroll
            for (int hh = 0; hh < 4; ++hh) {
                ps[hh] += __shfl_xor(ps[hh], off);
                pd[hh] += __shfl_xor(pd[hh], off);
            }
        }
        if (lane == 0) {
            ((float4*)es)[node] = make_float4(ps[0], ps[1], ps[2], ps[3]);
            ((float4*)ed)[node] = make_float4(pd[0], pd[1], pd[2], pd[3]);
        }
    } else if (blockIdx.x < kEncBlocks + kSctBlocks) {
        // raw edges: 4 per thread -> 4 independent atomic->store chains in flight
        int e0 = ((blockIdx.x - kEncBlocks) * 256 + threadIdx.x) * 4;
        int srcv[4], dstv[4];
#pragma unroll
        for (int u = 0; u < 4; ++u) {
            int e = e0 + u;
            if (e < kE) { srcv[u] = ei[e]; dstv[u] = ei[kE + e]; }
            else        { srcv[u] = -1; }
        }
#pragma unroll
        for (int u = 0; u < 4; ++u) {
            if (srcv[u] >= 0) {
                int pos = atomicAdd(&cursor[dstv[u]], 1);
                src_csr[pos] = srcv[u];
            }
        }
    } else {
        // self loops: exactly one per node, take the LAST slot of each run (no atomic)
        int d = (blockIdx.x - kEncBlocks - kSctBlocks) * 256 + threadIdx.x;
        if (d >= kN) return;
        src_csr[rowptr[d + 1] - 1] = d;
    }
}

// Fused GAT + GEMM + BN-stats. 1024 threads = 16 waves; block owns 16 dsts = one m-tile.
// Phase 1: wave w computes GAT for dst, z row -> LDS (padded stride 264).
// Phase 2: waves 0..NT-1 do one 16x16 MFMA tile each; BN col-stats -> disjoint LDS slices.
template <int DOUT>
__global__ void __launch_bounds__(1024) k_gatgemm(const int* __restrict__ rowptr,
                                                  const int* __restrict__ srcc,
                                                  const float* __restrict__ es,
                                                  const float* __restrict__ ed,
                                                  const ushort* __restrict__ h,
                                                  const ushort* __restrict__ Wt2l,
                                                  float* __restrict__ hnext,
                                                  float* __restrict__ bnrep_l) {
    constexpr int NT = DOUT / 16;
    constexpr int W = 2 * DOUT;
    __shared__ ushort zl[16][264];   // 16 z rows, padded (+8) -> 2-way max bank aliasing
    __shared__ float bnp[W];

    int tid = threadIdx.x;
    int w = tid >> 6, lane = tid & 63;
    int dst = blockIdx.x * 16 + w;   // kN % 16 == 0
    int start = rowptr[dst], end = rowptr[dst + 1];
    int deg = end - start;

    int e_l = lane >> 2, hh = lane & 3;    // score mapping
    int q = lane >> 4, c4 = lane & 15;     // gather mapping

    float edv = ed[dst * 4 + hh];
    float acc[4][4] = {};
    float s;

    if (deg <= 16) {
        int pos = start + e_l;
        int psafe = (pos < end) ? pos : start;
        int src = srcc[psafe];
        float v = es[src * 4 + hh] + edv;
        v = (v >= 0.f) ? v : 0.2f * v;
        if (pos >= end) v = -3e38f;

        uint2 hv[4];
#pragma unroll
        for (int t = 0; t < 4; ++t) {
            int p2 = start + t * 4 + q;
            int p2s = (p2 < end) ? p2 : start;
            int s2 = srcc[p2s];
            hv[t] = *reinterpret_cast<const uint2*>(h + (size_t)s2 * 64 + c4 * 4);
        }

        float cm = v;
        cm = fmaxf(cm, __shfl_xor(cm, 4));
        cm = fmaxf(cm, __shfl_xor(cm, 8));
        cm = fmaxf(cm, __shfl_xor(cm, 16));
        cm = fmaxf(cm, __shfl_xor(cm, 32));
        float p = __expf(v - cm);
        float cs = p;
        cs += __shfl_xor(cs, 4);
        cs += __shfl_xor(cs, 8);
        cs += __shfl_xor(cs, 16);
        cs += __shfl_xor(cs, 32);
        s = cs;

#pragma unroll
        for (int t = 0; t < 4; ++t) {
            int el = t * 4 + q;
            float p0 = __shfl(p, (el << 2) | 0);
            float p1 = __shfl(p, (el << 2) | 1);
            float p2 = __shfl(p, (el << 2) | 2);
            float p3 = __shfl(p, (el << 2) | 3);
            float c0 = __uint_as_float(hv[t].x << 16);
            float c1 = __uint_as_float(hv[t].x & 0xFFFF0000u);
            float c2 = __uint_as_float(hv[t].y << 16);
            float c3 = __uint_as_float(hv[t].y & 0xFFFF0000u);
            acc[0][0] += p0 * c0; acc[0][1] += p0 * c1; acc[0][2] += p0 * c2; acc[0][3] += p0 * c3;
            acc[1][0] += p1 * c0; acc[1][1] += p1 * c1; acc[1][2] += p1 * c2; acc[1][3] += p1 * c3;
            acc[2][0] += p2 * c0; acc[2][1] += p2 * c1; acc[2][2] += p2 * c2; acc[2][3] += p2 * c3;
            acc[3][0] += p3 * c0; acc[3][1] += p3 * c1; acc[3][2] += p3 * c2; acc[3][3] += p3 * c3;
        }
    } else {
        float m = -3e38f;
        s = 0.f;
        for (int cs0 = start; cs0 < end; cs0 += 16) {
            int pos = cs0 + e_l;
            int psafe = (pos < end) ? pos : start;
            int src = srcc[psafe];
            float v = es[src * 4 + hh] + edv;
            v = (v >= 0.f) ? v : 0.2f * v;
            if (pos >= end) v = -3e38f;

            float cm = v;
            cm = fmaxf(cm, __shfl_xor(cm, 4));
            cm = fmaxf(cm, __shfl_xor(cm, 8));
            cm = fmaxf(cm, __shfl_xor(cm, 16));
            cm = fmaxf(cm, __shfl_xor(cm, 32));
            float mn = fmaxf(m, cm);
            float scale = __expf(m - mn);
            float p = __expf(v - mn);
            float cth = p;
            cth += __shfl_xor(cth, 4);
            cth += __shfl_xor(cth, 8);
            cth += __shfl_xor(cth, 16);
            cth += __shfl_xor(cth, 32);
            s = s * scale + cth;
            m = mn;

            float sc0 = __shfl(scale, 0), sc1 = __shfl(scale, 1);
            float sc2 = __shfl(scale, 2), sc3 = __shfl(scale, 3);
#pragma unroll
            for (int c = 0; c < 4; ++c) {
                acc[0][c] *= sc0; acc[1][c] *= sc1; acc[2][c] *= sc2; acc[3][c] *= sc3;
            }
#pragma unroll
            for (int t = 0; t < 4; ++t) {
                int el = t * 4 + q;
                int p2 = cs0 + el;
                int p2s = (p2 < end) ? p2 : start;
                int s2 = srcc[p2s];
                uint2 hv = *reinterpret_cast<const uint2*>(h + (size_t)s2 * 64 + c4 * 4);
                float p0 = __shfl(p, (el << 2) | 0);
                float p1 = __shfl(p, (el << 2) | 1);
                float p2f = __shfl(p, (el << 2) | 2);
                float p3 = __shfl(p, (el << 2) | 3);
                float c0 = __uint_as_float(hv.x << 16);
                float c1 = __uint_as_float(hv.x & 0xFFFF0000u);
                float c2 = __uint_as_float(hv.y << 16);
                float c3 = __uint_as_float(hv.y & 0xFFFF0000u);
                acc[0][0] += p0 * c0;  acc[0][1] += p0 * c1;  acc[0][2] += p0 * c2;  acc[0][3] += p0 * c3;
                acc[1][0] += p1 * c0;  acc[1][1] += p1 * c1;  acc[1][2] += p1 * c2;  acc[1][3] += p1 * c3;
                acc[2][0] += p2f * c0; acc[2][1] += p2f * c1; acc[2][2] += p2f * c2; acc[2][3] += p2f * c3;
                acc[3][0] += p3 * c0;  acc[3][1] += p3 * c1;  acc[3][2] += p3 * c2;  acc[3][3] += p3 * c3;
            }
        }
    }

    float myinv = 0.25f / (s + 1e-16f);
    float inv0 = __shfl(myinv, 0), inv1 = __shfl(myinv, 1);
    float inv2 = __shfl(myinv, 2), inv3 = __shfl(myinv, 3);
#pragma unroll
    for (int c = 0; c < 4; ++c) {
        acc[0][c] *= inv0; acc[1][c] *= inv1; acc[2][c] *= inv2; acc[3][c] *= inv3;
    }
#pragma unroll
    for (int j = 0; j < 4; ++j) {
#pragma unroll
        for (int c = 0; c < 4; ++c) {
            float v = acc[j][c];
            v += __shfl_xor(v, 16);
            v += __shfl_xor(v, 32);
            acc[j][c] = v;
        }
    }
    if (q == 0) {
        ushort* zr = &zl[w][c4 * 4];
#pragma unroll
        for (int j = 0; j < 4; ++j) {
            ushort4 o;
            o.x = f2b(acc[j][0]); o.y = f2b(acc[j][1]);
            o.z = f2b(acc[j][2]); o.w = f2b(acc[j][3]);
            *reinterpret_cast<ushort4*>(zr + j * 64) = o;
        }
    }
    __syncthreads();

    // ---- phase 2: GEMM on the LDS z-tile ----
    f32x4 gacc = {0.f, 0.f, 0.f, 0.f};
    if (w < NT) {
        int row = lane & 15;
        int k0  = (lane >> 4) * 8;
        const ushort* za = &zl[row][k0];
        const ushort* wb = Wt2l + (size_t)(w * 16 + row) * 256 + k0;
#pragma unroll
        for (int ks = 0; ks < 8; ++ks) {
            bf16x8 a = *reinterpret_cast<const bf16x8*>(za + ks * 32);
            bf16x8 bb = *reinterpret_cast<const bf16x8*>(wb + ks * 32);
            gacc = __builtin_amdgcn_mfma_f32_16x16x32_bf16(a, bb, gacc, 0, 0, 0);
        }
        int col = lane & 15;
        int r0  = (lane >> 4) * 4;
        int m0  = blockIdx.x * 16;
#pragma unroll
        for (int r = 0; r < 4; ++r)
            hnext[(size_t)(m0 + r0 + r) * DOUT + w * 16 + col] = gacc[r];

        // BN col stats for this n-tile (disjoint 16-col slice per wave)
        float s0 = 0.f, q0 = 0.f;
#pragma unroll
        for (int r = 0; r < 4; ++r) { s0 += gacc[r]; q0 += gacc[r] * gacc[r]; }
        s0 += __shfl_xor(s0, 16); s0 += __shfl_xor(s0, 32);
        q0 += __shfl_xor(q0, 16); q0 += __shfl_xor(q0, 32);
        if (lane < 16) {
            bnp[w * 16 + lane]        = s0;
            bnp[DOUT + w * 16 + lane] = q0;
        }
    }
    __syncthreads();
    if (tid < W) {
        atomicAdd(&bnrep_l[(blockIdx.x & (kRep - 1)) * 128 + tid], bnp[tid]);
    }
}

// BN apply (layers 0,1) fused with NEXT layer's es/ed; sums kRep BN replicas.
__global__ void __launch_bounds__(256) k_bn_apply_att(const float* __restrict__ hnext,
                                                      const float* __restrict__ bnrep_l,
                                                      const float* __restrict__ g,
                                                      const float* __restrict__ be,
                                                      const float* __restrict__ ahat_next,
                                                      ushort* __restrict__ hcur,
                                                      float* __restrict__ es,
                                                      float* __restrict__ ed) {
    int node = blockIdx.x * 4 + (threadIdx.x >> 6);
    int lane = threadIdx.x & 63;
    float bs = 0.f, bq = 0.f;
#pragma unroll
    for (int r = 0; r < kRep; ++r) {
        bs += bnrep_l[r * 128 + lane];
        bq += bnrep_l[r * 128 + 64 + lane];
    }
    float mu = bs * (1.f / kN);
    float var = bq * (1.f / kN) - mu * mu;
    float v = g[lane] * (hnext[(size_t)node * 64 + lane] - mu) * rsqrtf(var + 1e-5f) + be[lane];
    v = fmaxf(v, 0.f);
    hcur[(size_t)node * 64 + lane] = f2b(v);

    float ps[4], pd[4];
#pragma unroll
    for (int hh = 0; hh < 4; ++hh) {
        ps[hh] = v * ahat_next[hh * 64 + lane];
        pd[hh] = v * ahat_next[256 + hh * 64 + lane];
    }
#pragma unroll
    for (int off = 1; off < 64; off <<= 1) {
#pragma unroll
        for (int hh = 0; hh < 4; ++hh) {
            ps[hh] += __shfl_xor(ps[hh], off);
            pd[hh] += __shfl_xor(pd[hh], off);
        }
    }
    if (lane == 0) {
        ((float4*)es)[node] = make_float4(ps[0], ps[1], ps[2], ps[3]);
        ((float4*)ed)[node] = make_float4(pd[0], pd[1], pd[2], pd[3]);
    }
}

// final BN apply (layer 2) fused with pooling partials; sums kRep BN replicas.
__global__ void __launch_bounds__(256) k_bn_apply32_pool(const float* __restrict__ hnext,
                                                         const float* __restrict__ bnrep_l,
                                                         const float* __restrict__ g,
                                                         const float* __restrict__ be,
                                                         const int* __restrict__ batch,
                                                         float* __restrict__ out_h,
                                                         float* __restrict__ gsum,
                                                         unsigned* __restrict__ gmaxe) {
    int tid = threadIdx.x;
    int i = blockIdx.x * 256 + tid;   // exactly kN*32 threads
    int n = i >> 5, c = i & 31;
    float bs = 0.f, bq = 0.f;
#pragma unroll
    for (int r = 0; r < kRep; ++r) {
        bs += bnrep_l[r * 128 + c];
        bq += bnrep_l[r * 128 + 32 + c];
    }
    float mu = bs * (1.f / kN);
    float var = bq * (1.f / kN) - mu * mu;
    float v = g[c] * (hnext[i] - mu) * rsqrtf(var + 1e-5f) + be[c];
    out_h[i] = v;

    __shared__ float ls[256];
    ls[tid] = v;
    __syncthreads();
    int nb0 = blockIdx.x * 8;
    int gfirst = batch[nb0], glast = batch[nb0 + 7];
    if (gfirst == glast) {
        if (tid < 32) {
            float s = 0.f;
            unsigned me = 0u;
#pragma unroll
            for (int r = 0; r < 8; ++r) {
                float vv = ls[r * 32 + tid];
                s += vv;
                unsigned e = enc_f(vv);
                me = (e > me) ? e : me;
            }
            atomicAdd(&gsum[gfirst * 32 + tid], s);
            atomicMax(&gmaxe[gfirst * 32 + tid], me);
        }
    } else {
        int gg = batch[n];
        atomicAdd(&gsum[gg * 32 + c], v);
        atomicMax(&gmaxe[gg * 32 + c], enc_f(v));
    }
}

// finalize pooling + both MLP heads (single block)
__global__ void __launch_bounds__(256) k_finish(const float* __restrict__ gsum,
                                                const unsigned* __restrict__ gmaxe,
                                                const int* __restrict__ batch,
                                                const float* __restrict__ ew1,
                                                const float* __restrict__ eb1,
                                                const float* __restrict__ ew2,
                                                const float* __restrict__ eb2,
                                                const float* __restrict__ mw1,
                                                const float* __restrict__ mb1,
                                                const float* __restrict__ mw2,
                                                const float* __restrict__ mb2,
                                                float* __restrict__ out_gemb,
                                                float* __restrict__ out_eth,
                                                float* __restrict__ out_man) {
    __shared__ int bound[kG + 1];
    __shared__ float ge[kG * 32];
    int tid = threadIdx.x;
    if (tid <= kG) {
        int lo = 0, hi = kN;
        while (lo < hi) { int mid = (lo + hi) >> 1; if (batch[mid] < tid) lo = mid + 1; else hi = mid; }
        bound[tid] = lo;
    }
    __syncthreads();
    for (int j = tid; j < kG * 32; j += 256) {
        int gg = j >> 5;
        int cnt = bound[gg + 1] - bound[gg];
        float sum = gsum[j];
        float mx = (cnt > 0) ? dec_f(gmaxe[j]) : 0.f;
        float mean = sum / fmaxf((float)cnt, 1.f);
        float e = (mean + mx + sum) * (1.f / 3.f);
        ge[j] = e;
        out_gemb[j] = e;
    }
    __syncthreads();
    if (tid < kG) {
        const float* row = &ge[tid * 32];
        float acc_e = eb2[0], acc_m = mb2[0];
#pragma unroll 4
        for (int j = 0; j < 16; ++j) {
            float he = eb1[j], hm = mb1[j];
            for (int k = 0; k < 32; ++k) {
                float v = row[k];
                he += v * ew1[k * 16 + j];
                hm += v * mw1[k * 16 + j];
            }
            acc_e += fmaxf(he, 0.f) * ew2[j];
            acc_m += fmaxf(hm, 0.f) * mw2[j];
        }
        out_eth[tid] = 1.f / (1.f + expf(-acc_e));
        out_man[tid] = 1.f / (1.f + expf(-acc_m));
    }
}

extern "C" void kernel_launch(void* const* d_in, const int* in_sizes, int n_in,
                              void* d_out, int out_size, void* d_ws, size_t ws_size,
                              hipStream_t stream) {
    const float* x     = (const float*)d_in[0];
    const int*   ei    = (const int*)d_in[1];
    const int*   batch = (const int*)d_in[2];
    const float* enc_w = (const float*)d_in[3];
    const float* enc_b = (const float*)d_in[4];

    float* ws = (float*)d_ws;
    ushort*   hcur  = (ushort*)(ws + OFF_HCUR);
    float*    hnext = ws + OFF_HNEXT;
    float*    es    = ws + OFF_ES;
    float*    ed    = ws + OFF_ED;
    int*      rowptr= (int*)(ws + OFF_ROWPTR);
    int*      srcc  = (int*)(ws + OFF_SRC);
    ushort*   Wt2   = (ushort*)(ws + OFF_WT2);
    float*    ahat  = ws + OFF_AHAT;
    int*      spart = (int*)(ws + OFF_SPART);
    int*      cursor= (int*)(ws + OFF_CURSOR);
    float*    bnrep = ws + OFF_BNREP;
    float*    gsum  = ws + OFF_GPOOL;
    unsigned* gmaxe = (unsigned*)(ws + OFF_GPOOL + 1600);

    float* out      = (float*)d_out;
    float* out_h    = out;                 // N*32
    float* out_gemb = out + 1600000;       // G*32
    float* out_eth  = out + 1601600;       // G
    float* out_man  = out + 1601650;       // G

    // ---- single zero-init: cursor + bnrep + gpool (contiguous) ----
    hipMemsetAsync(ws + OFF_CURSOR, 0, (kZeroEnd - OFF_CURSOR) * sizeof(float), stream);

    // ---- weight prep + dst histogram (fused) ----
    k_histprep<<<kPrepBlocks + kHistBlocks, 256, 0, stream>>>(
        ei, cursor,
        (const float*)d_in[5], (const float*)d_in[11], (const float*)d_in[17],
        (const float*)d_in[6], (const float*)d_in[12], (const float*)d_in[18],
        (const float*)d_in[7], (const float*)d_in[13], (const float*)d_in[19],
        ahat, Wt2);

    // ---- scan ----
    k_scan_local<<<kScanBlocks, 1024, 0, stream>>>(cursor, rowptr, spart);
    k_scan_part<<<1, 64, 0, stream>>>(spart);
    k_scan_add<<<kScanBlocks, 1024, 0, stream>>>(cursor, rowptr, spart);

    // ---- scatter + self-loops + encoder/layer-0 att (fused) ----
    k_scatter_enc<<<kEncBlocks + kSctBlocks + kLoopBlocks, 256, 0, stream>>>(
        ei, cursor, srcc, rowptr, x, enc_w, enc_b, ahat, hcur, es, ed);

    for (int l = 0; l < 3; ++l) {
        const float* gam = (const float*)d_in[9 + 6 * l];
        const float* bet = (const float*)d_in[10 + 6 * l];
        const ushort* Wt2l = Wt2 + l * 16384;
        float* bnrep_l = bnrep + l * kRep * 128;

        if (l < 2) {
            k_gatgemm<64><<<kN / 16, 1024, 0, stream>>>(rowptr, srcc, es, ed, hcur,
                                                        Wt2l, hnext, bnrep_l);
            k_bn_apply_att<<<kN / 4, 256, 0, stream>>>(hnext, bnrep_l, gam, bet,
                                                       ahat + (l + 1) * 512, hcur, es, ed);
        } else {
            k_gatgemm<32><<<kN / 16, 1024, 0, stream>>>(rowptr, srcc, es, ed, hcur,
                                                        Wt2l, hnext, bnrep_l);
            k_bn_apply32_pool<<<kN * 32 / 256, 256, 0, stream>>>(hnext, bnrep_l, gam, bet,
                                                                 batch, out_h, gsum, gmaxe);
        }
    }

    k_finish<<<1, 256, 0, stream>>>(gsum, gmaxe, batch,
                                    (const float*)d_in[23], (const float*)d_in[24],
                                    (const float*)d_in[25], (const float*)d_in[26],
                                    (const float*)d_in[27], (const float*)d_in[28],
                                    (const float*)d_in[29], (const float*)d_in[30],
                                    out_gemb, out_eth, out_man);
}

// Round 14
// 473.725 us; speedup vs baseline: 1.0905x; 1.0905x over previous
//
#include <hip/hip_runtime.h>
#include <math.h>

// Problem constants
constexpr int kN  = 50000;     // nodes
constexpr int kE  = 600000;    // raw edges
constexpr int kET = 650000;    // edges + self loops
constexpr int kG  = 50;        // graphs
constexpr int kH  = 4;         // heads
constexpr int kRep = 16;       // BN atomic replicas
constexpr int kRangeSz = 6250; // kN / 8 (XCD dst-range size)

// ws layout (float-slot offsets)
constexpr size_t OFF_HCUR   = 0;           // N*64 bf16
constexpr size_t OFF_HNEXT  = 1600000;     // N*64 f32
constexpr size_t OFF_Z      = 4800000;     // N*256 bf16
constexpr size_t OFF_ES     = 11200000;    // N*4 f32
constexpr size_t OFF_ED     = 11400000;    // N*4 f32
constexpr size_t OFF_ROWPTR = 14200000;    // (N+1) ints
constexpr size_t OFF_SRC    = 14320000;    // ET ushorts (1.3MB)
constexpr size_t OFF_WT2    = 14970000;    // 3 x 16384 bf16
constexpr size_t OFF_AHAT   = 15000000;    // 3 x 512 f32
constexpr size_t OFF_SPART  = 15002000;    // 64 ints
// ---- contiguous zero-init region (single memset) ----
constexpr size_t OFF_CURSOR = 15010000;    // N ints
constexpr size_t OFF_BNREP  = 15060000;    // 3 x kRep x 128 f32 = 6144
constexpr size_t OFF_GPOOL  = 15066144;    // gsum[1600] + gmaxe[1600]
constexpr size_t kZeroEnd   = 15069344;

constexpr int kScanBlocks = (kN + 1023) / 1024;   // 49
constexpr int kHistBlocks = (kET + 255) / 256;    // 2540
constexpr int kPrepBlocks = 163;
constexpr int kEncBlocks  = kN / 4;               // 12500
constexpr int kChunks     = (kE + 1023) / 1024;   // 586 (1024 edges/chunk)
constexpr int kSctBlocks  = kChunks * 8;          // 4688 (8 XCD ranges per chunk)
constexpr int kLoopBlocks = (kN + 255) / 256;     // 196

typedef __bf16 bf16x8 __attribute__((ext_vector_type(8)));
typedef float  f32x4  __attribute__((ext_vector_type(4)));

__device__ inline ushort f2b(float f) {  // RNE float->bf16 bits
    unsigned u = __float_as_uint(f);
    return (ushort)((u + 0x7FFFu + ((u >> 16) & 1u)) >> 16);
}
__device__ inline float b2f(ushort u) {
    return __uint_as_float(((unsigned)u) << 16);
}
__device__ inline unsigned enc_f(float f) {  // monotone float->uint
    unsigned b = __float_as_uint(f);
    return (b & 0x80000000u) ? ~b : (b | 0x80000000u);
}
__device__ inline float dec_f(unsigned u) {
    return __uint_as_float((u & 0x80000000u) ? (u & 0x7FFFFFFFu) : ~u);
}

__device__ inline void edge_pair(const int* __restrict__ ei, int e, int& src, int& dst) {
    if (e < kE) { src = ei[e]; dst = ei[kE + e]; }
    else        { src = e - kE; dst = e - kE; }
}

// ---------------- fused: weight prep (blocks 0..162) + dst histogram ----------------
__global__ void k_histprep(const int* __restrict__ ei, int* __restrict__ counts,
                           const float* __restrict__ w0, const float* __restrict__ w1,
                           const float* __restrict__ w2, const float* __restrict__ as0,
                           const float* __restrict__ as1, const float* __restrict__ as2,
                           const float* __restrict__ ad0, const float* __restrict__ ad1,
                           const float* __restrict__ ad2, float* __restrict__ ahat,
                           ushort* __restrict__ Wt2) {
    int b = blockIdx.x;
    if (b < 3) {
        const float* W  = (b == 0) ? w0 : (b == 1) ? w1 : w2;
        const float* As = (b == 0) ? as0 : (b == 1) ? as1 : as2;
        const float* Ad = (b == 0) ? ad0 : (b == 1) ? ad1 : ad2;
        int dout = (b == 2) ? 32 : 64;
        int i = threadIdx.x;
        int h = i >> 6, k = i & 63;
        const float* wr = W + (size_t)k * (4 * dout) + h * dout;
        float s1 = 0.f, s2 = 0.f;
        for (int c = 0; c < dout; ++c) {
            float w = wr[c];
            s1 += w * As[h * dout + c];
            s2 += w * Ad[h * dout + c];
        }
        ahat[b * 512 + i] = s1;
        ahat[b * 512 + 256 + i] = s2;
    } else if (b < kPrepBlocks) {
        int i = (b - 3) * 256 + threadIdx.x;   // over 40960
        if (i >= 40960) return;
        int l, li;
        if (i < 16384)      { l = 0; li = i; }
        else if (i < 32768) { l = 1; li = i - 16384; }
        else                { l = 2; li = i - 32768; }
        int dout = (l == 2) ? 32 : 64;
        const float* W = (l == 0) ? w0 : (l == 1) ? w1 : w2;
        int c = li >> 8, kk = li & 255;
        int h = kk >> 6, k = kk & 63;
        Wt2[l * 16384 + li] = f2b(W[(size_t)k * (4 * dout) + h * dout + c]);
    } else {
        int e = (b - kPrepBlocks) * 256 + threadIdx.x;
        if (e >= kET) return;
        int src, dst;
        edge_pair(ei, e, src, dst);
        atomicAdd(&counts[dst], 1);
    }
}

__global__ void __launch_bounds__(1024) k_scan_local(const int* __restrict__ counts,
                                                     int* __restrict__ rowptr,
                                                     int* __restrict__ partials) {
    int tid = threadIdx.x;
    int idx = blockIdx.x * 1024 + tid;
    int val = (idx < kN) ? counts[idx] : 0;
    int lane = tid & 63, w = tid >> 6;
    int x = val;
#pragma unroll
    for (int off = 1; off < 64; off <<= 1) {
        int t = __shfl_up(x, off);
        if (lane >= off) x += t;
    }
    __shared__ int wsum[16];
    if (lane == 63) wsum[w] = x;
    __syncthreads();
    if (w == 0 && lane < 16) {
        int y = wsum[lane];
#pragma unroll
        for (int off = 1; off < 16; off <<= 1) {
            int t = __shfl_up(y, off);
            if (lane >= off) y += t;
        }
        wsum[lane] = y;
    }
    __syncthreads();
    int incl = x + (w > 0 ? wsum[w - 1] : 0);
    if (idx < kN) rowptr[idx + 1] = incl;
    if (tid == 1023) partials[blockIdx.x] = incl;
}

__global__ void k_scan_part(int* __restrict__ partials) {
    int lane = threadIdx.x;
    int v = (lane < kScanBlocks) ? partials[lane] : 0;
    int x = v;
#pragma unroll
    for (int off = 1; off < 64; off <<= 1) {
        int t = __shfl_up(x, off);
        if (lane >= off) x += t;
    }
    if (lane < kScanBlocks) partials[lane] = x - v;
}

__global__ void __launch_bounds__(1024) k_scan_add(int* __restrict__ cursor,
                                                   int* __restrict__ rowptr,
                                                   const int* __restrict__ partials) {
    int idx = blockIdx.x * 1024 + threadIdx.x;
    if (idx >= kN) return;
    int incl = rowptr[idx + 1] + partials[blockIdx.x];
    rowptr[idx + 1] = incl;
    int val = cursor[idx];
    cursor[idx] = incl - val;
    if (idx == 0) rowptr[0] = 0;
}

// ---- fused: encoder+layer0 es/ed | XCD-binned raw-edge scatter | self-loop placement ----
__global__ void __launch_bounds__(256) k_scatter_enc(const int* __restrict__ ei,
                                                     int* __restrict__ cursor,
                                                     ushort* __restrict__ src_csr,
                                                     const int* __restrict__ rowptr,
                                                     const float* __restrict__ x,
                                                     const float* __restrict__ w,
                                                     const float* __restrict__ b,
                                                     const float* __restrict__ ahat0,
                                                     ushort* __restrict__ h,
                                                     float* __restrict__ es,
                                                     float* __restrict__ ed) {
    if (blockIdx.x < kEncBlocks) {
        int node = blockIdx.x * 4 + (threadIdx.x >> 6);
        int lane = threadIdx.x & 63;
        float acc = b[lane];
#pragma unroll
        for (int k = 0; k < 5; ++k) acc += x[node * 5 + k] * w[k * 64 + lane];
        h[(size_t)node * 64 + lane] = f2b(acc);

        float ps[4], pd[4];
#pragma unroll
        for (int hh = 0; hh < 4; ++hh) {
            ps[hh] = acc * ahat0[hh * 64 + lane];
            pd[hh] = acc * ahat0[256 + hh * 64 + lane];
        }
#pragma unroll
        for (int off = 1; off < 64; off <<= 1) {
#pragma unroll
            for (int hh = 0; hh < 4; ++hh) {
                ps[hh] += __shfl_xor(ps[hh], off);
                pd[hh] += __shfl_xor(pd[hh], off);
            }
        }
        if (lane == 0) {
            ((float4*)es)[node] = make_float4(ps[0], ps[1], ps[2], ps[3]);
            ((float4*)ed)[node] = make_float4(pd[0], pd[1], pd[2], pd[3]);
        }
    } else if (blockIdx.x < kEncBlocks + kSctBlocks) {
        // XCD-binned scatter: 8 blocks share an edge chunk; block handles dsts in its
        // range only. range = blockIdx & 7 matches the round-robin block->XCD mapping,
        // so each srcc/cursor region is written by ONE XCD -> no L2 line ping-pong.
        int bs = blockIdx.x - kEncBlocks;
        int chunk = bs >> 3;
        int range = blockIdx.x & 7;
        int dlo = range * kRangeSz;
        int e0 = (chunk * 256 + threadIdx.x) * 4;
        if (e0 >= kE) return;
        int4 dv = *reinterpret_cast<const int4*>(ei + kE + e0);
        int4 sv = *reinterpret_cast<const int4*>(ei + e0);
        int dstv[4] = {dv.x, dv.y, dv.z, dv.w};
        int srcv[4] = {sv.x, sv.y, sv.z, sv.w};
#pragma unroll
        for (int u = 0; u < 4; ++u) {
            if (e0 + u < kE && (unsigned)(dstv[u] - dlo) < (unsigned)kRangeSz) {
                int pos = atomicAdd(&cursor[dstv[u]], 1);
                src_csr[pos] = (ushort)srcv[u];
            }
        }
    } else {
        // self loops: exactly one per node, take the LAST slot of each run (no atomic)
        int d = (blockIdx.x - kEncBlocks - kSctBlocks) * 256 + threadIdx.x;
        if (d >= kN) return;
        src_csr[rowptr[d + 1] - 1] = (ushort)d;
    }
}

// Fused edge-softmax + aggregation. One wave per dst.
__global__ void __launch_bounds__(256) k_gat(const int* __restrict__ rowptr,
                                             const ushort* __restrict__ srcc,
                                             const float* __restrict__ es,
                                             const float* __restrict__ ed,
                                             const ushort* __restrict__ h,
                                             ushort* __restrict__ z) {
    int wid = threadIdx.x >> 6;
    int lane = threadIdx.x & 63;
    int dst = blockIdx.x * 4 + wid;   // kN % 4 == 0
    int start = rowptr[dst], end = rowptr[dst + 1];
    int deg = end - start;

    int e_l = lane >> 2, hh = lane & 3;    // score mapping
    int q = lane >> 4, c4 = lane & 15;     // gather mapping

    float edv = ed[dst * 4 + hh];
    float acc[4][4] = {};
    float s;

    if (deg <= 16) {
        int pos = start + e_l;
        int psafe = (pos < end) ? pos : start;
        int src = srcc[psafe];
        float v = es[src * 4 + hh] + edv;
        v = (v >= 0.f) ? v : 0.2f * v;
        if (pos >= end) v = -3e38f;

        uint2 hv[4];
#pragma unroll
        for (int t = 0; t < 4; ++t) {
            int p2 = start + t * 4 + q;
            int p2s = (p2 < end) ? p2 : start;
            int s2 = srcc[p2s];
            hv[t] = *reinterpret_cast<const uint2*>(h + (size_t)s2 * 64 + c4 * 4);
        }

        float cm = v;
        cm = fmaxf(cm, __shfl_xor(cm, 4));
        cm = fmaxf(cm, __shfl_xor(cm, 8));
        cm = fmaxf(cm, __shfl_xor(cm, 16));
        cm = fmaxf(cm, __shfl_xor(cm, 32));
        float p = __expf(v - cm);
        float cs = p;
        cs += __shfl_xor(cs, 4);
        cs += __shfl_xor(cs, 8);
        cs += __shfl_xor(cs, 16);
        cs += __shfl_xor(cs, 32);
        s = cs;

#pragma unroll
        for (int t = 0; t < 4; ++t) {
            int el = t * 4 + q;
            float p0 = __shfl(p, (el << 2) | 0);
            float p1 = __shfl(p, (el << 2) | 1);
            float p2 = __shfl(p, (el << 2) | 2);
            float p3 = __shfl(p, (el << 2) | 3);
            float c0 = __uint_as_float(hv[t].x << 16);
            float c1 = __uint_as_float(hv[t].x & 0xFFFF0000u);
            float c2 = __uint_as_float(hv[t].y << 16);
            float c3 = __uint_as_float(hv[t].y & 0xFFFF0000u);
            acc[0][0] += p0 * c0; acc[0][1] += p0 * c1; acc[0][2] += p0 * c2; acc[0][3] += p0 * c3;
            acc[1][0] += p1 * c0; acc[1][1] += p1 * c1; acc[1][2] += p1 * c2; acc[1][3] += p1 * c3;
            acc[2][0] += p2 * c0; acc[2][1] += p2 * c1; acc[2][2] += p2 * c2; acc[2][3] += p2 * c3;
            acc[3][0] += p3 * c0; acc[3][1] += p3 * c1; acc[3][2] += p3 * c2; acc[3][3] += p3 * c3;
        }
    } else {
        float m = -3e38f;
        s = 0.f;
        for (int cs0 = start; cs0 < end; cs0 += 16) {
            int pos = cs0 + e_l;
            int psafe = (pos < end) ? pos : start;
            int src = srcc[psafe];
            float v = es[src * 4 + hh] + edv;
            v = (v >= 0.f) ? v : 0.2f * v;
            if (pos >= end) v = -3e38f;

            float cm = v;
            cm = fmaxf(cm, __shfl_xor(cm, 4));
            cm = fmaxf(cm, __shfl_xor(cm, 8));
            cm = fmaxf(cm, __shfl_xor(cm, 16));
            cm = fmaxf(cm, __shfl_xor(cm, 32));
            float mn = fmaxf(m, cm);
            float scale = __expf(m - mn);
            float p = __expf(v - mn);
            float cth = p;
            cth += __shfl_xor(cth, 4);
            cth += __shfl_xor(cth, 8);
            cth += __shfl_xor(cth, 16);
            cth += __shfl_xor(cth, 32);
            s = s * scale + cth;
            m = mn;

            float sc0 = __shfl(scale, 0), sc1 = __shfl(scale, 1);
            float sc2 = __shfl(scale, 2), sc3 = __shfl(scale, 3);
#pragma unroll
            for (int c = 0; c < 4; ++c) {
                acc[0][c] *= sc0; acc[1][c] *= sc1; acc[2][c] *= sc2; acc[3][c] *= sc3;
            }
#pragma unroll
            for (int t = 0; t < 4; ++t) {
                int el = t * 4 + q;
                int p2 = cs0 + el;
                int p2s = (p2 < end) ? p2 : start;
                int s2 = srcc[p2s];
                uint2 hv = *reinterpret_cast<const uint2*>(h + (size_t)s2 * 64 + c4 * 4);
                float p0 = __shfl(p, (el << 2) | 0);
                float p1 = __shfl(p, (el << 2) | 1);
                float p2f = __shfl(p, (el << 2) | 2);
                float p3 = __shfl(p, (el << 2) | 3);
                float c0 = __uint_as_float(hv.x << 16);
                float c1 = __uint_as_float(hv.x & 0xFFFF0000u);
                float c2 = __uint_as_float(hv.y << 16);
                float c3 = __uint_as_float(hv.y & 0xFFFF0000u);
                acc[0][0] += p0 * c0;  acc[0][1] += p0 * c1;  acc[0][2] += p0 * c2;  acc[0][3] += p0 * c3;
                acc[1][0] += p1 * c0;  acc[1][1] += p1 * c1;  acc[1][2] += p1 * c2;  acc[1][3] += p1 * c3;
                acc[2][0] += p2f * c0; acc[2][1] += p2f * c1; acc[2][2] += p2f * c2; acc[2][3] += p2f * c3;
                acc[3][0] += p3 * c0;  acc[3][1] += p3 * c1;  acc[3][2] += p3 * c2;  acc[3][3] += p3 * c3;
            }
        }
    }

    float myinv = 0.25f / (s + 1e-16f);
    float inv0 = __shfl(myinv, 0), inv1 = __shfl(myinv, 1);
    float inv2 = __shfl(myinv, 2), inv3 = __shfl(myinv, 3);
#pragma unroll
    for (int c = 0; c < 4; ++c) {
        acc[0][c] *= inv0; acc[1][c] *= inv1; acc[2][c] *= inv2; acc[3][c] *= inv3;
    }
#pragma unroll
    for (int j = 0; j < 4; ++j) {
#pragma unroll
        for (int c = 0; c < 4; ++c) {
            float v = acc[j][c];
            v += __shfl_xor(v, 16);
            v += __shfl_xor(v, 32);
            acc[j][c] = v;
        }
    }
    if (q == 0) {
        ushort* zr = z + (size_t)dst * 256 + c4 * 4;
#pragma unroll
        for (int j = 0; j < 4; ++j) {
            ushort4 o;
            o.x = f2b(acc[j][0]); o.y = f2b(acc[j][1]);
            o.z = f2b(acc[j][2]); o.w = f2b(acc[j][3]);
            *reinterpret_cast<ushort4*>(zr + j * 64) = o;
        }
    }
}

// MFMA GEMM: one wave = one 16x16 output tile (8 MFMAs). Fused BN stats ->
// LDS combine -> 2*DOUT atomicAdds into replica row (blockIdx & (kRep-1)).
template <int DOUT>
__global__ void __launch_bounds__(256) k_zgemm(const ushort* __restrict__ z,
                                               const ushort* __restrict__ Wt2l,
                                               float* __restrict__ hnext,
                                               float* __restrict__ bnrep_l) {
    constexpr int NT = DOUT / 16;
    constexpr int W = 2 * DOUT;
    __shared__ float pl[4][W];
    int tid = threadIdx.x;
    int widx = tid >> 6, lane = tid & 63;
    int wid = blockIdx.x * 4 + widx;
    int mtile = wid / NT;
    int nt = wid - mtile * NT;
    bool active = (mtile < kN / 16);
    int m0 = mtile * 16;
    int n0 = nt * 16;

    int row = lane & 15;
    int k0  = (lane >> 4) * 8;

    // zero-init LDS partials
    for (int j = tid; j < 4 * W; j += 256) (&pl[0][0])[j] = 0.f;

    f32x4 acc = {0.f, 0.f, 0.f, 0.f};
    if (active) {
        const ushort* za = z + (size_t)(m0 + row) * 256 + k0;
        const ushort* wb = Wt2l + (size_t)(n0 + row) * 256 + k0;
#pragma unroll
        for (int ks = 0; ks < 8; ++ks) {
            bf16x8 a = *reinterpret_cast<const bf16x8*>(za + ks * 32);
            bf16x8 b = *reinterpret_cast<const bf16x8*>(wb + ks * 32);
            acc = __builtin_amdgcn_mfma_f32_16x16x32_bf16(a, b, acc, 0, 0, 0);
        }
        int col = lane & 15;
        int r0  = (lane >> 4) * 4;
#pragma unroll
        for (int r = 0; r < 4; ++r)
            hnext[(size_t)(m0 + r0 + r) * DOUT + n0 + col] = acc[r];
    }

    // per-wave column stats (zeros if inactive)
    float s0 = 0.f, q0 = 0.f;
#pragma unroll
    for (int r = 0; r < 4; ++r) { s0 += acc[r]; q0 += acc[r] * acc[r]; }
    s0 += __shfl_xor(s0, 16); s0 += __shfl_xor(s0, 32);
    q0 += __shfl_xor(q0, 16); q0 += __shfl_xor(q0, 32);
    __syncthreads();   // init complete before per-wave writes
    if (lane < 16) {
        pl[widx][n0 + lane]        = s0;
        pl[widx][DOUT + n0 + lane] = q0;
    }
    __syncthreads();
    if (tid < W) {
        float t = pl[0][tid] + pl[1][tid] + pl[2][tid] + pl[3][tid];
        atomicAdd(&bnrep_l[(blockIdx.x & (kRep - 1)) * 128 + tid], t);
    }
}

// BN apply (layers 0,1) fused with NEXT layer's es/ed; sums kRep BN replicas.
__global__ void __launch_bounds__(256) k_bn_apply_att(const float* __restrict__ hnext,
                                                      const float* __restrict__ bnrep_l,
                                                      const float* __restrict__ g,
                                                      const float* __restrict__ be,
                                                      const float* __restrict__ ahat_next,
                                                      ushort* __restrict__ hcur,
                                                      float* __restrict__ es,
                                                      float* __restrict__ ed) {
    int node = blockIdx.x * 4 + (threadIdx.x >> 6);
    int lane = threadIdx.x & 63;
    float bs = 0.f, bq = 0.f;
#pragma unroll
    for (int r = 0; r < kRep; ++r) {
        bs += bnrep_l[r * 128 + lane];
        bq += bnrep_l[r * 128 + 64 + lane];
    }
    float mu = bs * (1.f / kN);
    float var = bq * (1.f / kN) - mu * mu;
    float v = g[lane] * (hnext[(size_t)node * 64 + lane] - mu) * rsqrtf(var + 1e-5f) + be[lane];
    v = fmaxf(v, 0.f);
    hcur[(size_t)node * 64 + lane] = f2b(v);

    float ps[4], pd[4];
#pragma unroll
    for (int hh = 0; hh < 4; ++hh) {
        ps[hh] = v * ahat_next[hh * 64 + lane];
        pd[hh] = v * ahat_next[256 + hh * 64 + lane];
    }
#pragma unroll
    for (int off = 1; off < 64; off <<= 1) {
#pragma unroll
        for (int hh = 0; hh < 4; ++hh) {
            ps[hh] += __shfl_xor(ps[hh], off);
            pd[hh] += __shfl_xor(pd[hh], off);
        }
    }
    if (lane == 0) {
        ((float4*)es)[node] = make_float4(ps[0], ps[1], ps[2], ps[3]);
        ((float4*)ed)[node] = make_float4(pd[0], pd[1], pd[2], pd[3]);
    }
}

// final BN apply (layer 2) fused with pooling partials; sums kRep BN replicas.
__global__ void __launch_bounds__(256) k_bn_apply32_pool(const float* __restrict__ hnext,
                                                         const float* __restrict__ bnrep_l,
                                                         const float* __restrict__ g,
                                                         const float* __restrict__ be,
                                                         const int* __restrict__ batch,
                                                         float* __restrict__ out_h,
                                                         float* __restrict__ gsum,
                                                         unsigned* __restrict__ gmaxe) {
    int tid = threadIdx.x;
    int i = blockIdx.x * 256 + tid;   // exactly kN*32 threads
    int n = i >> 5, c = i & 31;
    float bs = 0.f, bq = 0.f;
#pragma unroll
    for (int r = 0; r < kRep; ++r) {
        bs += bnrep_l[r * 128 + c];
        bq += bnrep_l[r * 128 + 32 + c];
    }
    float mu = bs * (1.f / kN);
    float var = bq * (1.f / kN) - mu * mu;
    float v = g[c] * (hnext[i] - mu) * rsqrtf(var + 1e-5f) + be[c];
    out_h[i] = v;

    __shared__ float ls[256];
    ls[tid] = v;
    __syncthreads();
    int nb0 = blockIdx.x * 8;
    int gfirst = batch[nb0], glast = batch[nb0 + 7];
    if (gfirst == glast) {
        if (tid < 32) {
            float s = 0.f;
            unsigned me = 0u;
#pragma unroll
            for (int r = 0; r < 8; ++r) {
                float vv = ls[r * 32 + tid];
                s += vv;
                unsigned e = enc_f(vv);
                me = (e > me) ? e : me;
            }
            atomicAdd(&gsum[gfirst * 32 + tid], s);
            atomicMax(&gmaxe[gfirst * 32 + tid], me);
        }
    } else {
        int gg = batch[n];
        atomicAdd(&gsum[gg * 32 + c], v);
        atomicMax(&gmaxe[gg * 32 + c], enc_f(v));
    }
}

// finalize pooling + both MLP heads (single block)
__global__ void __launch_bounds__(256) k_finish(const float* __restrict__ gsum,
                                                const unsigned* __restrict__ gmaxe,
                                                const int* __restrict__ batch,
                                                const float* __restrict__ ew1,
                                                const float* __restrict__ eb1,
                                                const float* __restrict__ ew2,
                                                const float* __restrict__ eb2,
                                                const float* __restrict__ mw1,
                                                const float* __restrict__ mb1,
                                                const float* __restrict__ mw2,
                                                const float* __restrict__ mb2,
                                                float* __restrict__ out_gemb,
                                                float* __restrict__ out_eth,
                                                float* __restrict__ out_man) {
    __shared__ int bound[kG + 1];
    __shared__ float ge[kG * 32];
    int tid = threadIdx.x;
    if (tid <= kG) {
        int lo = 0, hi = kN;
        while (lo < hi) { int mid = (lo + hi) >> 1; if (batch[mid] < tid) lo = mid + 1; else hi = mid; }
        bound[tid] = lo;
    }
    __syncthreads();
    for (int j = tid; j < kG * 32; j += 256) {
        int gg = j >> 5;
        int cnt = bound[gg + 1] - bound[gg];
        float sum = gsum[j];
        float mx = (cnt > 0) ? dec_f(gmaxe[j]) : 0.f;
        float mean = sum / fmaxf((float)cnt, 1.f);
        float e = (mean + mx + sum) * (1.f / 3.f);
        ge[j] = e;
        out_gemb[j] = e;
    }
    __syncthreads();
    if (tid < kG) {
        const float* row = &ge[tid * 32];
        float acc_e = eb2[0], acc_m = mb2[0];
#pragma unroll 4
        for (int j = 0; j < 16; ++j) {
            float he = eb1[j], hm = mb1[j];
            for (int k = 0; k < 32; ++k) {
                float v = row[k];
                he += v * ew1[k * 16 + j];
                hm += v * mw1[k * 16 + j];
            }
            acc_e += fmaxf(he, 0.f) * ew2[j];
            acc_m += fmaxf(hm, 0.f) * mw2[j];
        }
        out_eth[tid] = 1.f / (1.f + expf(-acc_e));
        out_man[tid] = 1.f / (1.f + expf(-acc_m));
    }
}

extern "C" void kernel_launch(void* const* d_in, const int* in_sizes, int n_in,
                              void* d_out, int out_size, void* d_ws, size_t ws_size,
                              hipStream_t stream) {
    const float* x     = (const float*)d_in[0];
    const int*   ei    = (const int*)d_in[1];
    const int*   batch = (const int*)d_in[2];
    const float* enc_w = (const float*)d_in[3];
    const float* enc_b = (const float*)d_in[4];

    float* ws = (float*)d_ws;
    ushort*   hcur  = (ushort*)(ws + OFF_HCUR);
    float*    hnext = ws + OFF_HNEXT;
    ushort*   z     = (ushort*)(ws + OFF_Z);
    float*    es    = ws + OFF_ES;
    float*    ed    = ws + OFF_ED;
    int*      rowptr= (int*)(ws + OFF_ROWPTR);
    ushort*   srcc  = (ushort*)(ws + OFF_SRC);
    ushort*   Wt2   = (ushort*)(ws + OFF_WT2);
    float*    ahat  = ws + OFF_AHAT;
    int*      spart = (int*)(ws + OFF_SPART);
    int*      cursor= (int*)(ws + OFF_CURSOR);
    float*    bnrep = ws + OFF_BNREP;
    float*    gsum  = ws + OFF_GPOOL;
    unsigned* gmaxe = (unsigned*)(ws + OFF_GPOOL + 1600);

    float* out      = (float*)d_out;
    float* out_h    = out;                 // N*32
    float* out_gemb = out + 1600000;       // G*32
    float* out_eth  = out + 1601600;       // G
    float* out_man  = out + 1601650;       // G

    // ---- single zero-init: cursor + bnrep + gpool (contiguous) ----
    hipMemsetAsync(ws + OFF_CURSOR, 0, (kZeroEnd - OFF_CURSOR) * sizeof(float), stream);

    // ---- weight prep + dst histogram (fused) ----
    k_histprep<<<kPrepBlocks + kHistBlocks, 256, 0, stream>>>(
        ei, cursor,
        (const float*)d_in[5], (const float*)d_in[11], (const float*)d_in[17],
        (const float*)d_in[6], (const float*)d_in[12], (const float*)d_in[18],
        (const float*)d_in[7], (const float*)d_in[13], (const float*)d_in[19],
        ahat, Wt2);

    // ---- scan ----
    k_scan_local<<<kScanBlocks, 1024, 0, stream>>>(cursor, rowptr, spart);
    k_scan_part<<<1, 64, 0, stream>>>(spart);
    k_scan_add<<<kScanBlocks, 1024, 0, stream>>>(cursor, rowptr, spart);

    // ---- scatter (XCD-binned) + self-loops + encoder/layer-0 att (fused) ----
    k_scatter_enc<<<kEncBlocks + kSctBlocks + kLoopBlocks, 256, 0, stream>>>(
        ei, cursor, srcc, rowptr, x, enc_w, enc_b, ahat, hcur, es, ed);

    for (int l = 0; l < 3; ++l) {
        const float* gam = (const float*)d_in[9 + 6 * l];
        const float* bet = (const float*)d_in[10 + 6 * l];
        const ushort* Wt2l = Wt2 + l * 16384;
        float* bnrep_l = bnrep + l * kRep * 128;

        k_gat<<<kN / 4, 256, 0, stream>>>(rowptr, srcc, es, ed, hcur, z);

        if (l < 2) {
            k_zgemm<64><<<3125, 256, 0, stream>>>(z, Wt2l, hnext, bnrep_l);
            k_bn_apply_att<<<kN / 4, 256, 0, stream>>>(hnext, bnrep_l, gam, bet,
                                                       ahat + (l + 1) * 512, hcur, es, ed);
        } else {
            k_zgemm<32><<<1563, 256, 0, stream>>>(z, Wt2l, hnext, bnrep_l);
            k_bn_apply32_pool<<<kN * 32 / 256, 256, 0, stream>>>(hnext, bnrep_l, gam, bet,
                                                                 batch, out_h, gsum, gmaxe);
        }
    }

    k_finish<<<1, 256, 0, stream>>>(gsum, gmaxe, batch,
                                    (const float*)d_in[23], (const float*)d_in[24],
                                    (const float*)d_in[25], (const float*)d_in[26],
                                    (const float*)d_in[27], (const float*)d_in[28],
                                    (const float*)d_in[29], (const float*)d_in[30],
                                    out_gemb, out_eth, out_man);
}

// Round 15
// 473.028 us; speedup vs baseline: 1.0921x; 1.0015x over previous
//
#include <hip/hip_runtime.h>
#include <math.h>

// Problem constants
constexpr int kN  = 50000;     // nodes
constexpr int kE  = 600000;    // raw edges
constexpr int kET = 650000;    // edges + self loops
constexpr int kG  = 50;        // graphs
constexpr int kH  = 4;         // heads
constexpr int kRep = 16;       // BN atomic replicas
constexpr int kRangeSz = 6250; // kN / 8 (XCD dst-range size)

// ws layout (float-slot offsets)
constexpr size_t OFF_HCUR   = 0;           // N*64 bf16
constexpr size_t OFF_HNEXT  = 1600000;     // N*64 f32
constexpr size_t OFF_Z      = 4800000;     // N*256 bf16
constexpr size_t OFF_ES     = 11200000;    // N*4 f32
constexpr size_t OFF_ED     = 11400000;    // N*4 f32
constexpr size_t OFF_ROWPTR = 14200000;    // (N+1) ints
constexpr size_t OFF_SRC    = 14320000;    // ET ushorts (1.3MB)
constexpr size_t OFF_WT2    = 14970000;    // 3 x 16384 bf16
constexpr size_t OFF_AHAT   = 15000000;    // 3 x 512 f32
constexpr size_t OFF_SPART  = 15002000;    // 64 ints
// ---- contiguous zero-init region (single memset) ----
constexpr size_t OFF_CURSOR = 15010000;    // N ints
constexpr size_t OFF_BNREP  = 15060000;    // 3 x kRep x 128 f32 = 6144
constexpr size_t OFF_GPOOL  = 15066144;    // gsum[1600] + gmaxe[1600]
constexpr size_t kZeroEnd   = 15069344;

constexpr int kScanBlocks = (kN + 1023) / 1024;   // 49
constexpr int kHistBlocks = (kET + 255) / 256;    // 2540
constexpr int kPrepBlocks = 163;
constexpr int kEncBlocks  = kN / 4;               // 12500
constexpr int kChunks     = (kE + 1023) / 1024;   // 586
constexpr int kSctBlocks  = kChunks * 8;          // 4688
constexpr int kLoopBlocks = (kN + 255) / 256;     // 196

typedef __bf16 bf16x8 __attribute__((ext_vector_type(8)));
typedef float  f32x4  __attribute__((ext_vector_type(4)));

__device__ inline ushort f2b(float f) {  // RNE float->bf16 bits
    unsigned u = __float_as_uint(f);
    return (ushort)((u + 0x7FFFu + ((u >> 16) & 1u)) >> 16);
}
__device__ inline float b2f(ushort u) {
    return __uint_as_float(((unsigned)u) << 16);
}
__device__ inline unsigned enc_f(float f) {  // monotone float->uint
    unsigned b = __float_as_uint(f);
    return (b & 0x80000000u) ? ~b : (b | 0x80000000u);
}
__device__ inline float dec_f(unsigned u) {
    return __uint_as_float((u & 0x80000000u) ? (u & 0x7FFFFFFFu) : ~u);
}

__device__ inline void edge_pair(const int* __restrict__ ei, int e, int& src, int& dst) {
    if (e < kE) { src = ei[e]; dst = ei[kE + e]; }
    else        { src = e - kE; dst = e - kE; }
}

// ---------------- fused: weight prep (blocks 0..162) + dst histogram ----------------
__global__ void k_histprep(const int* __restrict__ ei, int* __restrict__ counts,
                           const float* __restrict__ w0, const float* __restrict__ w1,
                           const float* __restrict__ w2, const float* __restrict__ as0,
                           const float* __restrict__ as1, const float* __restrict__ as2,
                           const float* __restrict__ ad0, const float* __restrict__ ad1,
                           const float* __restrict__ ad2, float* __restrict__ ahat,
                           ushort* __restrict__ Wt2) {
    int b = blockIdx.x;
    if (b < 3) {
        const float* W  = (b == 0) ? w0 : (b == 1) ? w1 : w2;
        const float* As = (b == 0) ? as0 : (b == 1) ? as1 : as2;
        const float* Ad = (b == 0) ? ad0 : (b == 1) ? ad1 : ad2;
        int dout = (b == 2) ? 32 : 64;
        int i = threadIdx.x;
        int h = i >> 6, k = i & 63;
        const float* wr = W + (size_t)k * (4 * dout) + h * dout;
        float s1 = 0.f, s2 = 0.f;
        for (int c = 0; c < dout; ++c) {
            float w = wr[c];
            s1 += w * As[h * dout + c];
            s2 += w * Ad[h * dout + c];
        }
        ahat[b * 512 + i] = s1;
        ahat[b * 512 + 256 + i] = s2;
    } else if (b < kPrepBlocks) {
        int i = (b - 3) * 256 + threadIdx.x;   // over 40960
        if (i >= 40960) return;
        int l, li;
        if (i < 16384)      { l = 0; li = i; }
        else if (i < 32768) { l = 1; li = i - 16384; }
        else                { l = 2; li = i - 32768; }
        int dout = (l == 2) ? 32 : 64;
        const float* W = (l == 0) ? w0 : (l == 1) ? w1 : w2;
        int c = li >> 8, kk = li & 255;
        int h = kk >> 6, k = kk & 63;
        Wt2[l * 16384 + li] = f2b(W[(size_t)k * (4 * dout) + h * dout + c]);
    } else {
        int e = (b - kPrepBlocks) * 256 + threadIdx.x;
        if (e >= kET) return;
        int src, dst;
        edge_pair(ei, e, src, dst);
        atomicAdd(&counts[dst], 1);
    }
}

__global__ void __launch_bounds__(1024) k_scan_local(const int* __restrict__ counts,
                                                     int* __restrict__ rowptr,
                                                     int* __restrict__ partials) {
    int tid = threadIdx.x;
    int idx = blockIdx.x * 1024 + tid;
    int val = (idx < kN) ? counts[idx] : 0;
    int lane = tid & 63, w = tid >> 6;
    int x = val;
#pragma unroll
    for (int off = 1; off < 64; off <<= 1) {
        int t = __shfl_up(x, off);
        if (lane >= off) x += t;
    }
    __shared__ int wsum[16];
    if (lane == 63) wsum[w] = x;
    __syncthreads();
    if (w == 0 && lane < 16) {
        int y = wsum[lane];
#pragma unroll
        for (int off = 1; off < 16; off <<= 1) {
            int t = __shfl_up(y, off);
            if (lane >= off) y += t;
        }
        wsum[lane] = y;
    }
    __syncthreads();
    int incl = x + (w > 0 ? wsum[w - 1] : 0);
    if (idx < kN) rowptr[idx + 1] = incl;
    if (tid == 1023) partials[blockIdx.x] = incl;
}

__global__ void k_scan_part(int* __restrict__ partials) {
    int lane = threadIdx.x;
    int v = (lane < kScanBlocks) ? partials[lane] : 0;
    int x = v;
#pragma unroll
    for (int off = 1; off < 64; off <<= 1) {
        int t = __shfl_up(x, off);
        if (lane >= off) x += t;
    }
    if (lane < kScanBlocks) partials[lane] = x - v;
}

__global__ void __launch_bounds__(1024) k_scan_add(int* __restrict__ cursor,
                                                   int* __restrict__ rowptr,
                                                   const int* __restrict__ partials) {
    int idx = blockIdx.x * 1024 + threadIdx.x;
    if (idx >= kN) return;
    int incl = rowptr[idx + 1] + partials[blockIdx.x];
    rowptr[idx + 1] = incl;
    int val = cursor[idx];
    cursor[idx] = incl - val;
    if (idx == 0) rowptr[0] = 0;
}

// ---- fused: encoder+layer0 es/ed | XCD-binned raw-edge scatter | self-loop placement ----
__global__ void __launch_bounds__(256) k_scatter_enc(const int* __restrict__ ei,
                                                     int* __restrict__ cursor,
                                                     ushort* __restrict__ src_csr,
                                                     const int* __restrict__ rowptr,
                                                     const float* __restrict__ x,
                                                     const float* __restrict__ w,
                                                     const float* __restrict__ b,
                                                     const float* __restrict__ ahat0,
                                                     ushort* __restrict__ h,
                                                     float* __restrict__ es,
                                                     float* __restrict__ ed) {
    if (blockIdx.x < kEncBlocks) {
        int node = blockIdx.x * 4 + (threadIdx.x >> 6);
        int lane = threadIdx.x & 63;
        float acc = b[lane];
#pragma unroll
        for (int k = 0; k < 5; ++k) acc += x[node * 5 + k] * w[k * 64 + lane];
        h[(size_t)node * 64 + lane] = f2b(acc);

        float ps[4], pd[4];
#pragma unroll
        for (int hh = 0; hh < 4; ++hh) {
            ps[hh] = acc * ahat0[hh * 64 + lane];
            pd[hh] = acc * ahat0[256 + hh * 64 + lane];
        }
#pragma unroll
        for (int off = 1; off < 64; off <<= 1) {
#pragma unroll
            for (int hh = 0; hh < 4; ++hh) {
                ps[hh] += __shfl_xor(ps[hh], off);
                pd[hh] += __shfl_xor(pd[hh], off);
            }
        }
        if (lane == 0) {
            ((float4*)es)[node] = make_float4(ps[0], ps[1], ps[2], ps[3]);
            ((float4*)ed)[node] = make_float4(pd[0], pd[1], pd[2], pd[3]);
        }
    } else if (blockIdx.x < kEncBlocks + kSctBlocks) {
        int bs = blockIdx.x - kEncBlocks;
        int chunk = bs >> 3;
        int range = blockIdx.x & 7;
        int dlo = range * kRangeSz;
        int e0 = (chunk * 256 + threadIdx.x) * 4;
        if (e0 >= kE) return;
        int4 dv = *reinterpret_cast<const int4*>(ei + kE + e0);
        int4 sv = *reinterpret_cast<const int4*>(ei + e0);
        int dstv[4] = {dv.x, dv.y, dv.z, dv.w};
        int srcv[4] = {sv.x, sv.y, sv.z, sv.w};
#pragma unroll
        for (int u = 0; u < 4; ++u) {
            if (e0 + u < kE && (unsigned)(dstv[u] - dlo) < (unsigned)kRangeSz) {
                int pos = atomicAdd(&cursor[dstv[u]], 1);
                src_csr[pos] = (ushort)srcv[u];
            }
        }
    } else {
        int d = (blockIdx.x - kEncBlocks - kSctBlocks) * 256 + threadIdx.x;
        if (d >= kN) return;
        src_csr[rowptr[d + 1] - 1] = (ushort)d;
    }
}

// Fused edge-softmax + aggregation. One wave per dst; lane = channel.
// Per-edge p weights go through wave-private LDS (broadcast reads), so the
// per-channel accumulators are lane-local: NO cross-lane reduce at the end.
__global__ void __launch_bounds__(256) k_gat(const int* __restrict__ rowptr,
                                             const ushort* __restrict__ srcc,
                                             const float* __restrict__ es,
                                             const float* __restrict__ ed,
                                             const ushort* __restrict__ h,
                                             ushort* __restrict__ z) {
    __shared__ float pls[4][72];   // per-wave: p[64] + scale/inv[4] @ offset 64
    int wid = threadIdx.x >> 6;
    int lane = threadIdx.x & 63;
    int dst = blockIdx.x * 4 + wid;   // kN % 4 == 0
    int start = rowptr[dst], end = rowptr[dst + 1];

    int e_l = lane >> 2, hh = lane & 3;    // score mapping
    int c = lane;                          // channel this lane owns

    float edv = ed[dst * 4 + hh];
    float acc0 = 0.f, acc1 = 0.f, acc2 = 0.f, acc3 = 0.f;
    float m = -3e38f, s = 0.f;
    float* pw = pls[wid];

    for (int cs0 = start; cs0 < end; cs0 += 16) {
        // ---- scores for up to 16 edges (lane = e_l*4+hh) ----
        int pos = cs0 + e_l;
        int psafe = (pos < end) ? pos : start;
        int src = srcc[psafe];
        float v = es[src * 4 + hh] + edv;
        v = (v >= 0.f) ? v : 0.2f * v;
        if (pos >= end) v = -3e38f;

        float cm = v;
        cm = fmaxf(cm, __shfl_xor(cm, 4));
        cm = fmaxf(cm, __shfl_xor(cm, 8));
        cm = fmaxf(cm, __shfl_xor(cm, 16));
        cm = fmaxf(cm, __shfl_xor(cm, 32));
        float mn = fmaxf(m, cm);
        float scale = __expf(m - mn);      // 0 on first chunk (m = -3e38)
        float p = __expf(v - mn);          // 0 for padded lanes
        float cth = p;
        cth += __shfl_xor(cth, 4);
        cth += __shfl_xor(cth, 8);
        cth += __shfl_xor(cth, 16);
        cth += __shfl_xor(cth, 32);
        s = s * scale + cth;
        m = mn;

        // publish p (by lane layout e*4+h) and per-head scale
        pw[lane] = p;
        if (lane < 4) pw[64 + lane] = scale;
        // wave-private LDS: compiler inserts lgkmcnt before dependent reads
        float4 scv = *reinterpret_cast<const float4*>(&pw[64]);
        acc0 *= scv.x; acc1 *= scv.y; acc2 *= scv.z; acc3 *= scv.w;

        // ---- weighted accumulate: lane owns channel c; p via broadcast LDS reads ----
        int nedge = min(end - cs0, 16);
#pragma unroll 4
        for (int e = 0; e < nedge; ++e) {
            int srcE = srcc[cs0 + e];                       // wave-uniform broadcast load
            float4 pe = *reinterpret_cast<const float4*>(&pw[e * 4]);
            float hc = b2f(h[(size_t)srcE * 64 + c]);       // 64 lanes -> 128B coalesced
            acc0 += pe.x * hc;
            acc1 += pe.y * hc;
            acc2 += pe.z * hc;
            acc3 += pe.w * hc;
        }
    }

    // normalize: per-head inv via the same LDS slot
    if (lane < 4) pw[64 + lane] = 0.25f / (s + 1e-16f);
    float4 iv = *reinterpret_cast<const float4*>(&pw[64]);

    ushort* zr = z + (size_t)dst * 256 + c;
    zr[0]   = f2b(acc0 * iv.x);
    zr[64]  = f2b(acc1 * iv.y);
    zr[128] = f2b(acc2 * iv.z);
    zr[192] = f2b(acc3 * iv.w);
}

// MFMA GEMM: one wave = one 16x16 output tile (8 MFMAs). Fused BN stats ->
// LDS combine -> 2*DOUT atomicAdds into replica row (blockIdx & (kRep-1)).
template <int DOUT>
__global__ void __launch_bounds__(256) k_zgemm(const ushort* __restrict__ z,
                                               const ushort* __restrict__ Wt2l,
                                               float* __restrict__ hnext,
                                               float* __restrict__ bnrep_l) {
    constexpr int NT = DOUT / 16;
    constexpr int W = 2 * DOUT;
    __shared__ float pl[4][W];
    int tid = threadIdx.x;
    int widx = tid >> 6, lane = tid & 63;
    int wid = blockIdx.x * 4 + widx;
    int mtile = wid / NT;
    int nt = wid - mtile * NT;
    bool active = (mtile < kN / 16);
    int m0 = mtile * 16;
    int n0 = nt * 16;

    int row = lane & 15;
    int k0  = (lane >> 4) * 8;

    for (int j = tid; j < 4 * W; j += 256) (&pl[0][0])[j] = 0.f;

    f32x4 acc = {0.f, 0.f, 0.f, 0.f};
    if (active) {
        const ushort* za = z + (size_t)(m0 + row) * 256 + k0;
        const ushort* wb = Wt2l + (size_t)(n0 + row) * 256 + k0;
#pragma unroll
        for (int ks = 0; ks < 8; ++ks) {
            bf16x8 a = *reinterpret_cast<const bf16x8*>(za + ks * 32);
            bf16x8 b = *reinterpret_cast<const bf16x8*>(wb + ks * 32);
            acc = __builtin_amdgcn_mfma_f32_16x16x32_bf16(a, b, acc, 0, 0, 0);
        }
        int col = lane & 15;
        int r0  = (lane >> 4) * 4;
#pragma unroll
        for (int r = 0; r < 4; ++r)
            hnext[(size_t)(m0 + r0 + r) * DOUT + n0 + col] = acc[r];
    }

    float s0 = 0.f, q0 = 0.f;
#pragma unroll
    for (int r = 0; r < 4; ++r) { s0 += acc[r]; q0 += acc[r] * acc[r]; }
    s0 += __shfl_xor(s0, 16); s0 += __shfl_xor(s0, 32);
    q0 += __shfl_xor(q0, 16); q0 += __shfl_xor(q0, 32);
    __syncthreads();
    if (lane < 16) {
        pl[widx][n0 + lane]        = s0;
        pl[widx][DOUT + n0 + lane] = q0;
    }
    __syncthreads();
    if (tid < W) {
        float t = pl[0][tid] + pl[1][tid] + pl[2][tid] + pl[3][tid];
        atomicAdd(&bnrep_l[(blockIdx.x & (kRep - 1)) * 128 + tid], t);
    }
}

// BN apply (layers 0,1) fused with NEXT layer's es/ed; sums kRep BN replicas.
__global__ void __launch_bounds__(256) k_bn_apply_att(const float* __restrict__ hnext,
                                                      const float* __restrict__ bnrep_l,
                                                      const float* __restrict__ g,
                                                      const float* __restrict__ be,
                                                      const float* __restrict__ ahat_next,
                                                      ushort* __restrict__ hcur,
                                                      float* __restrict__ es,
                                                      float* __restrict__ ed) {
    int node = blockIdx.x * 4 + (threadIdx.x >> 6);
    int lane = threadIdx.x & 63;
    float bs = 0.f, bq = 0.f;
#pragma unroll
    for (int r = 0; r < kRep; ++r) {
        bs += bnrep_l[r * 128 + lane];
        bq += bnrep_l[r * 128 + 64 + lane];
    }
    float mu = bs * (1.f / kN);
    float var = bq * (1.f / kN) - mu * mu;
    float v = g[lane] * (hnext[(size_t)node * 64 + lane] - mu) * rsqrtf(var + 1e-5f) + be[lane];
    v = fmaxf(v, 0.f);
    hcur[(size_t)node * 64 + lane] = f2b(v);

    float ps[4], pd[4];
#pragma unroll
    for (int hh = 0; hh < 4; ++hh) {
        ps[hh] = v * ahat_next[hh * 64 + lane];
        pd[hh] = v * ahat_next[256 + hh * 64 + lane];
    }
#pragma unroll
    for (int off = 1; off < 64; off <<= 1) {
#pragma unroll
        for (int hh = 0; hh < 4; ++hh) {
            ps[hh] += __shfl_xor(ps[hh], off);
            pd[hh] += __shfl_xor(pd[hh], off);
        }
    }
    if (lane == 0) {
        ((float4*)es)[node] = make_float4(ps[0], ps[1], ps[2], ps[3]);
        ((float4*)ed)[node] = make_float4(pd[0], pd[1], pd[2], pd[3]);
    }
}

// final BN apply (layer 2) fused with pooling partials; sums kRep BN replicas.
__global__ void __launch_bounds__(256) k_bn_apply32_pool(const float* __restrict__ hnext,
                                                         const float* __restrict__ bnrep_l,
                                                         const float* __restrict__ g,
                                                         const float* __restrict__ be,
                                                         const int* __restrict__ batch,
                                                         float* __restrict__ out_h,
                                                         float* __restrict__ gsum,
                                                         unsigned* __restrict__ gmaxe) {
    int tid = threadIdx.x;
    int i = blockIdx.x * 256 + tid;   // exactly kN*32 threads
    int n = i >> 5, c = i & 31;
    float bs = 0.f, bq = 0.f;
#pragma unroll
    for (int r = 0; r < kRep; ++r) {
        bs += bnrep_l[r * 128 + c];
        bq += bnrep_l[r * 128 + 32 + c];
    }
    float mu = bs * (1.f / kN);
    float var = bq * (1.f / kN) - mu * mu;
    float v = g[c] * (hnext[i] - mu) * rsqrtf(var + 1e-5f) + be[c];
    out_h[i] = v;

    __shared__ float ls[256];
    ls[tid] = v;
    __syncthreads();
    int nb0 = blockIdx.x * 8;
    int gfirst = batch[nb0], glast = batch[nb0 + 7];
    if (gfirst == glast) {
        if (tid < 32) {
            float s = 0.f;
            unsigned me = 0u;
#pragma unroll
            for (int r = 0; r < 8; ++r) {
                float vv = ls[r * 32 + tid];
                s += vv;
                unsigned e = enc_f(vv);
                me = (e > me) ? e : me;
            }
            atomicAdd(&gsum[gfirst * 32 + tid], s);
            atomicMax(&gmaxe[gfirst * 32 + tid], me);
        }
    } else {
        int gg = batch[n];
        atomicAdd(&gsum[gg * 32 + c], v);
        atomicMax(&gmaxe[gg * 32 + c], enc_f(v));
    }
}

// finalize pooling + both MLP heads (single block)
__global__ void __launch_bounds__(256) k_finish(const float* __restrict__ gsum,
                                                const unsigned* __restrict__ gmaxe,
                                                const int* __restrict__ batch,
                                                const float* __restrict__ ew1,
                                                const float* __restrict__ eb1,
                                                const float* __restrict__ ew2,
                                                const float* __restrict__ eb2,
                                                const float* __restrict__ mw1,
                                                const float* __restrict__ mb1,
                                                const float* __restrict__ mw2,
                                                const float* __restrict__ mb2,
                                                float* __restrict__ out_gemb,
                                                float* __restrict__ out_eth,
                                                float* __restrict__ out_man) {
    __shared__ int bound[kG + 1];
    __shared__ float ge[kG * 32];
    int tid = threadIdx.x;
    if (tid <= kG) {
        int lo = 0, hi = kN;
        while (lo < hi) { int mid = (lo + hi) >> 1; if (batch[mid] < tid) lo = mid + 1; else hi = mid; }
        bound[tid] = lo;
    }
    __syncthreads();
    for (int j = tid; j < kG * 32; j += 256) {
        int gg = j >> 5;
        int cnt = bound[gg + 1] - bound[gg];
        float sum = gsum[j];
        float mx = (cnt > 0) ? dec_f(gmaxe[j]) : 0.f;
        float mean = sum / fmaxf((float)cnt, 1.f);
        float e = (mean + mx + sum) * (1.f / 3.f);
        ge[j] = e;
        out_gemb[j] = e;
    }
    __syncthreads();
    if (tid < kG) {
        const float* row = &ge[tid * 32];
        float acc_e = eb2[0], acc_m = mb2[0];
#pragma unroll 4
        for (int j = 0; j < 16; ++j) {
            float he = eb1[j], hm = mb1[j];
            for (int k = 0; k < 32; ++k) {
                float v = row[k];
                he += v * ew1[k * 16 + j];
                hm += v * mw1[k * 16 + j];
            }
            acc_e += fmaxf(he, 0.f) * ew2[j];
            acc_m += fmaxf(hm, 0.f) * mw2[j];
        }
        out_eth[tid] = 1.f / (1.f + expf(-acc_e));
        out_man[tid] = 1.f / (1.f + expf(-acc_m));
    }
}

extern "C" void kernel_launch(void* const* d_in, const int* in_sizes, int n_in,
                              void* d_out, int out_size, void* d_ws, size_t ws_size,
                              hipStream_t stream) {
    const float* x     = (const float*)d_in[0];
    const int*   ei    = (const int*)d_in[1];
    const int*   batch = (const int*)d_in[2];
    const float* enc_w = (const float*)d_in[3];
    const float* enc_b = (const float*)d_in[4];

    float* ws = (float*)d_ws;
    ushort*   hcur  = (ushort*)(ws + OFF_HCUR);
    float*    hnext = ws + OFF_HNEXT;
    ushort*   z     = (ushort*)(ws + OFF_Z);
    float*    es    = ws + OFF_ES;
    float*    ed    = ws + OFF_ED;
    int*      rowptr= (int*)(ws + OFF_ROWPTR);
    ushort*   srcc  = (ushort*)(ws + OFF_SRC);
    ushort*   Wt2   = (ushort*)(ws + OFF_WT2);
    float*    ahat  = ws + OFF_AHAT;
    int*      spart = (int*)(ws + OFF_SPART);
    int*      cursor= (int*)(ws + OFF_CURSOR);
    float*    bnrep = ws + OFF_BNREP;
    float*    gsum  = ws + OFF_GPOOL;
    unsigned* gmaxe = (unsigned*)(ws + OFF_GPOOL + 1600);

    float* out      = (float*)d_out;
    float* out_h    = out;                 // N*32
    float* out_gemb = out + 1600000;       // G*32
    float* out_eth  = out + 1601600;       // G
    float* out_man  = out + 1601650;       // G

    // ---- single zero-init: cursor + bnrep + gpool (contiguous) ----
    hipMemsetAsync(ws + OFF_CURSOR, 0, (kZeroEnd - OFF_CURSOR) * sizeof(float), stream);

    // ---- weight prep + dst histogram (fused) ----
    k_histprep<<<kPrepBlocks + kHistBlocks, 256, 0, stream>>>(
        ei, cursor,
        (const float*)d_in[5], (const float*)d_in[11], (const float*)d_in[17],
        (const float*)d_in[6], (const float*)d_in[12], (const float*)d_in[18],
        (const float*)d_in[7], (const float*)d_in[13], (const float*)d_in[19],
        ahat, Wt2);

    // ---- scan ----
    k_scan_local<<<kScanBlocks, 1024, 0, stream>>>(cursor, rowptr, spart);
    k_scan_part<<<1, 64, 0, stream>>>(spart);
    k_scan_add<<<kScanBlocks, 1024, 0, stream>>>(cursor, rowptr, spart);

    // ---- scatter (XCD-binned) + self-loops + encoder/layer-0 att (fused) ----
    k_scatter_enc<<<kEncBlocks + kSctBlocks + kLoopBlocks, 256, 0, stream>>>(
        ei, cursor, srcc, rowptr, x, enc_w, enc_b, ahat, hcur, es, ed);

    for (int l = 0; l < 3; ++l) {
        const float* gam = (const float*)d_in[9 + 6 * l];
        const float* bet = (const float*)d_in[10 + 6 * l];
        const ushort* Wt2l = Wt2 + l * 16384;
        float* bnrep_l = bnrep + l * kRep * 128;

        k_gat<<<kN / 4, 256, 0, stream>>>(rowptr, srcc, es, ed, hcur, z);

        if (l < 2) {
            k_zgemm<64><<<3125, 256, 0, stream>>>(z, Wt2l, hnext, bnrep_l);
            k_bn_apply_att<<<kN / 4, 256, 0, stream>>>(hnext, bnrep_l, gam, bet,
                                                       ahat + (l + 1) * 512, hcur, es, ed);
        } else {
            k_zgemm<32><<<1563, 256, 0, stream>>>(z, Wt2l, hnext, bnrep_l);
            k_bn_apply32_pool<<<kN * 32 / 256, 256, 0, stream>>>(hnext, bnrep_l, gam, bet,
                                                                 batch, out_h, gsum, gmaxe);
        }
    }

    k_finish<<<1, 256, 0, stream>>>(gsum, gmaxe, batch,
                                    (const float*)d_in[23], (const float*)d_in[24],
                                    (const float*)d_in[25], (const float*)d_in[26],
                                    (const float*)d_in[27], (const float*)d_in[28],
                                    (const float*)d_in[29], (const float*)d_in[30],
                                    out_gemb, out_eth, out_man);
}

// Round 16
// 451.051 us; speedup vs baseline: 1.1453x; 1.0487x over previous
//
#include <hip/hip_runtime.h>
#include <math.h>

// Problem constants
constexpr int kN  = 50000;     // nodes
constexpr int kE  = 600000;    // raw edges
constexpr int kET = 650000;    // edges + self loops
constexpr int kG  = 50;        // graphs
constexpr int kH  = 4;         // heads
constexpr int kRep = 16;       // BN atomic replicas
constexpr int kRangeSz = 6250; // kN / 8 (XCD dst-range size)

// ws layout (float-slot offsets)
constexpr size_t OFF_HCUR   = 0;           // N*64 bf16
constexpr size_t OFF_HNEXT  = 1600000;     // N*64 f32
constexpr size_t OFF_Z      = 4800000;     // N*256 bf16
constexpr size_t OFF_ES     = 11200000;    // N*4 f32
constexpr size_t OFF_ED     = 11400000;    // N*4 f32
constexpr size_t OFF_ROWPTR = 14200000;    // (N+1) ints
constexpr size_t OFF_SRC    = 14320000;    // ET ushorts (1.3MB)
constexpr size_t OFF_WT2    = 14970000;    // 3 x 16384 bf16
constexpr size_t OFF_AHAT   = 15000000;    // 3 x 512 f32
constexpr size_t OFF_SPART  = 15002000;    // 64 ints
// ---- contiguous zero-init region (single memset) ----
constexpr size_t OFF_CURSOR = 15010000;    // N ints
constexpr size_t OFF_BNREP  = 15060000;    // 3 x kRep x 128 f32 = 6144
constexpr size_t OFF_GPOOL  = 15066144;    // gsum[1600] + gmaxe[1600]
constexpr size_t kZeroEnd   = 15069344;

constexpr int kScanBlocks = (kN + 1023) / 1024;   // 49
constexpr int kHistBlocks = (kET + 255) / 256;    // 2540
constexpr int kPrepBlocks = 163;
constexpr int kEncBlocks  = kN / 4;               // 12500
constexpr int kChunks     = (kE + 1023) / 1024;   // 586
constexpr int kSctBlocks  = kChunks * 8;          // 4688
constexpr int kLoopBlocks = (kN + 255) / 256;     // 196

typedef __bf16 bf16x8 __attribute__((ext_vector_type(8)));
typedef float  f32x4  __attribute__((ext_vector_type(4)));

__device__ inline ushort f2b(float f) {  // RNE float->bf16 bits
    unsigned u = __float_as_uint(f);
    return (ushort)((u + 0x7FFFu + ((u >> 16) & 1u)) >> 16);
}
__device__ inline float b2f(ushort u) {
    return __uint_as_float(((unsigned)u) << 16);
}
__device__ inline unsigned enc_f(float f) {  // monotone float->uint
    unsigned b = __float_as_uint(f);
    return (b & 0x80000000u) ? ~b : (b | 0x80000000u);
}
__device__ inline float dec_f(unsigned u) {
    return __uint_as_float((u & 0x80000000u) ? (u & 0x7FFFFFFFu) : ~u);
}

__device__ inline void edge_pair(const int* __restrict__ ei, int e, int& src, int& dst) {
    if (e < kE) { src = ei[e]; dst = ei[kE + e]; }
    else        { src = e - kE; dst = e - kE; }
}

// ---------------- fused: weight prep (blocks 0..162) + dst histogram ----------------
__global__ void k_histprep(const int* __restrict__ ei, int* __restrict__ counts,
                           const float* __restrict__ w0, const float* __restrict__ w1,
                           const float* __restrict__ w2, const float* __restrict__ as0,
                           const float* __restrict__ as1, const float* __restrict__ as2,
                           const float* __restrict__ ad0, const float* __restrict__ ad1,
                           const float* __restrict__ ad2, float* __restrict__ ahat,
                           ushort* __restrict__ Wt2) {
    int b = blockIdx.x;
    if (b < 3) {
        const float* W  = (b == 0) ? w0 : (b == 1) ? w1 : w2;
        const float* As = (b == 0) ? as0 : (b == 1) ? as1 : as2;
        const float* Ad = (b == 0) ? ad0 : (b == 1) ? ad1 : ad2;
        int dout = (b == 2) ? 32 : 64;
        int i = threadIdx.x;
        int h = i >> 6, k = i & 63;
        const float* wr = W + (size_t)k * (4 * dout) + h * dout;
        float s1 = 0.f, s2 = 0.f;
        for (int c = 0; c < dout; ++c) {
            float w = wr[c];
            s1 += w * As[h * dout + c];
            s2 += w * Ad[h * dout + c];
        }
        ahat[b * 512 + i] = s1;
        ahat[b * 512 + 256 + i] = s2;
    } else if (b < kPrepBlocks) {
        int i = (b - 3) * 256 + threadIdx.x;   // over 40960
        if (i >= 40960) return;
        int l, li;
        if (i < 16384)      { l = 0; li = i; }
        else if (i < 32768) { l = 1; li = i - 16384; }
        else                { l = 2; li = i - 32768; }
        int dout = (l == 2) ? 32 : 64;
        const float* W = (l == 0) ? w0 : (l == 1) ? w1 : w2;
        int c = li >> 8, kk = li & 255;
        int h = kk >> 6, k = kk & 63;
        Wt2[l * 16384 + li] = f2b(W[(size_t)k * (4 * dout) + h * dout + c]);
    } else {
        int e = (b - kPrepBlocks) * 256 + threadIdx.x;
        if (e >= kET) return;
        int src, dst;
        edge_pair(ei, e, src, dst);
        atomicAdd(&counts[dst], 1);
    }
}

__global__ void __launch_bounds__(1024) k_scan_local(const int* __restrict__ counts,
                                                     int* __restrict__ rowptr,
                                                     int* __restrict__ partials) {
    int tid = threadIdx.x;
    int idx = blockIdx.x * 1024 + tid;
    int val = (idx < kN) ? counts[idx] : 0;
    int lane = tid & 63, w = tid >> 6;
    int x = val;
#pragma unroll
    for (int off = 1; off < 64; off <<= 1) {
        int t = __shfl_up(x, off);
        if (lane >= off) x += t;
    }
    __shared__ int wsum[16];
    if (lane == 63) wsum[w] = x;
    __syncthreads();
    if (w == 0 && lane < 16) {
        int y = wsum[lane];
#pragma unroll
        for (int off = 1; off < 16; off <<= 1) {
            int t = __shfl_up(y, off);
            if (lane >= off) y += t;
        }
        wsum[lane] = y;
    }
    __syncthreads();
    int incl = x + (w > 0 ? wsum[w - 1] : 0);
    if (idx < kN) rowptr[idx + 1] = incl;
    if (tid == 1023) partials[blockIdx.x] = incl;
}

__global__ void k_scan_part(int* __restrict__ partials) {
    int lane = threadIdx.x;
    int v = (lane < kScanBlocks) ? partials[lane] : 0;
    int x = v;
#pragma unroll
    for (int off = 1; off < 64; off <<= 1) {
        int t = __shfl_up(x, off);
        if (lane >= off) x += t;
    }
    if (lane < kScanBlocks) partials[lane] = x - v;
}

__global__ void __launch_bounds__(1024) k_scan_add(int* __restrict__ cursor,
                                                   int* __restrict__ rowptr,
                                                   const int* __restrict__ partials) {
    int idx = blockIdx.x * 1024 + threadIdx.x;
    if (idx >= kN) return;
    int incl = rowptr[idx + 1] + partials[blockIdx.x];
    rowptr[idx + 1] = incl;
    int val = cursor[idx];
    cursor[idx] = incl - val;
    if (idx == 0) rowptr[0] = 0;
}

// ---- fused: encoder+layer0 es/ed | XCD-binned raw-edge scatter | self-loop placement ----
__global__ void __launch_bounds__(256) k_scatter_enc(const int* __restrict__ ei,
                                                     int* __restrict__ cursor,
                                                     ushort* __restrict__ src_csr,
                                                     const int* __restrict__ rowptr,
                                                     const float* __restrict__ x,
                                                     const float* __restrict__ w,
                                                     const float* __restrict__ b,
                                                     const float* __restrict__ ahat0,
                                                     ushort* __restrict__ h,
                                                     float* __restrict__ es,
                                                     float* __restrict__ ed) {
    if (blockIdx.x < kEncBlocks) {
        int node = blockIdx.x * 4 + (threadIdx.x >> 6);
        int lane = threadIdx.x & 63;
        float acc = b[lane];
#pragma unroll
        for (int k = 0; k < 5; ++k) acc += x[node * 5 + k] * w[k * 64 + lane];
        h[(size_t)node * 64 + lane] = f2b(acc);

        float ps[4], pd[4];
#pragma unroll
        for (int hh = 0; hh < 4; ++hh) {
            ps[hh] = acc * ahat0[hh * 64 + lane];
            pd[hh] = acc * ahat0[256 + hh * 64 + lane];
        }
#pragma unroll
        for (int off = 1; off < 64; off <<= 1) {
#pragma unroll
            for (int hh = 0; hh < 4; ++hh) {
                ps[hh] += __shfl_xor(ps[hh], off);
                pd[hh] += __shfl_xor(pd[hh], off);
            }
        }
        if (lane == 0) {
            ((float4*)es)[node] = make_float4(ps[0], ps[1], ps[2], ps[3]);
            ((float4*)ed)[node] = make_float4(pd[0], pd[1], pd[2], pd[3]);
        }
    } else if (blockIdx.x < kEncBlocks + kSctBlocks) {
        int bs = blockIdx.x - kEncBlocks;
        int chunk = bs >> 3;
        int range = blockIdx.x & 7;
        int dlo = range * kRangeSz;
        int e0 = (chunk * 256 + threadIdx.x) * 4;
        if (e0 >= kE) return;
        int4 dv = *reinterpret_cast<const int4*>(ei + kE + e0);
        int4 sv = *reinterpret_cast<const int4*>(ei + e0);
        int dstv[4] = {dv.x, dv.y, dv.z, dv.w};
        int srcv[4] = {sv.x, sv.y, sv.z, sv.w};
#pragma unroll
        for (int u = 0; u < 4; ++u) {
            if (e0 + u < kE && (unsigned)(dstv[u] - dlo) < (unsigned)kRangeSz) {
                int pos = atomicAdd(&cursor[dstv[u]], 1);
                src_csr[pos] = (ushort)srcv[u];
            }
        }
    } else {
        int d = (blockIdx.x - kEncBlocks - kSctBlocks) * 256 + threadIdx.x;
        if (d >= kN) return;
        src_csr[rowptr[d + 1] - 1] = (ushort)d;
    }
}

// Fused edge-softmax + aggregation. One wave per dst; lane = channel.
// Score phase publishes src indices + p weights to LDS; accumulate phase reads
// them via broadcast LDS loads, so the 16 h-gathers issue with full MLP.
__global__ void __launch_bounds__(256) k_gat(const int* __restrict__ rowptr,
                                             const ushort* __restrict__ srcc,
                                             const float* __restrict__ es,
                                             const float* __restrict__ ed,
                                             const ushort* __restrict__ h,
                                             ushort* __restrict__ z) {
    __shared__ float pls[4][72];   // per-wave: p[64] + scale/inv[4] @ offset 64
    __shared__ int   sls[4][16];   // per-wave: src indices of the chunk
    int wid = threadIdx.x >> 6;
    int lane = threadIdx.x & 63;
    int dst = blockIdx.x * 4 + wid;   // kN % 4 == 0
    int start = rowptr[dst], end = rowptr[dst + 1];

    int e_l = lane >> 2, hh = lane & 3;    // score mapping
    int c = lane;                          // channel this lane owns

    float edv = ed[dst * 4 + hh];
    float acc0 = 0.f, acc1 = 0.f, acc2 = 0.f, acc3 = 0.f;
    float m = -3e38f, s = 0.f;
    float* pw = pls[wid];
    int*   sw = sls[wid];

    for (int cs0 = start; cs0 < end; cs0 += 16) {
        // ---- scores for up to 16 edges (lane = e_l*4+hh) ----
        int pos = cs0 + e_l;
        int psafe = (pos < end) ? pos : start;
        int src = srcc[psafe];
        float v = es[src * 4 + hh] + edv;
        v = (v >= 0.f) ? v : 0.2f * v;
        if (pos >= end) v = -3e38f;

        float cm = v;
        cm = fmaxf(cm, __shfl_xor(cm, 4));
        cm = fmaxf(cm, __shfl_xor(cm, 8));
        cm = fmaxf(cm, __shfl_xor(cm, 16));
        cm = fmaxf(cm, __shfl_xor(cm, 32));
        float mn = fmaxf(m, cm);
        float scale = __expf(m - mn);      // 0 on first chunk (m = -3e38)
        float p = __expf(v - mn);          // 0 for padded lanes
        float cth = p;
        cth += __shfl_xor(cth, 4);
        cth += __shfl_xor(cth, 8);
        cth += __shfl_xor(cth, 16);
        cth += __shfl_xor(cth, 32);
        s = s * scale + cth;
        m = mn;

        // publish p, src, and per-head scale (src already in registers from score phase)
        pw[lane] = p;
        if (hh == 0) sw[e_l] = src;
        if (lane < 4) pw[64 + lane] = scale;
        float4 scv = *reinterpret_cast<const float4*>(&pw[64]);
        acc0 *= scv.x; acc1 *= scv.y; acc2 *= scv.z; acc3 *= scv.w;

        // ---- weighted accumulate: src + p via broadcast LDS reads; gathers pipelined ----
        int nedge = min(end - cs0, 16);
#pragma unroll 4
        for (int e = 0; e < nedge; ++e) {
            int srcE = sw[e];                               // LDS broadcast (~30cy)
            float4 pe = *reinterpret_cast<const float4*>(&pw[e * 4]);
            float hc = b2f(h[(size_t)srcE * 64 + c]);       // 64 lanes -> 128B coalesced
            acc0 += pe.x * hc;
            acc1 += pe.y * hc;
            acc2 += pe.z * hc;
            acc3 += pe.w * hc;
        }
    }

    // normalize: per-head inv via the same LDS slot
    if (lane < 4) pw[64 + lane] = 0.25f / (s + 1e-16f);
    float4 iv = *reinterpret_cast<const float4*>(&pw[64]);

    ushort* zr = z + (size_t)dst * 256 + c;
    zr[0]   = f2b(acc0 * iv.x);
    zr[64]  = f2b(acc1 * iv.y);
    zr[128] = f2b(acc2 * iv.z);
    zr[192] = f2b(acc3 * iv.w);
}

// MFMA GEMM: one wave = one 16x16 output tile (8 MFMAs). Fused BN stats ->
// LDS combine -> 2*DOUT atomicAdds into replica row (blockIdx & (kRep-1)).
template <int DOUT>
__global__ void __launch_bounds__(256) k_zgemm(const ushort* __restrict__ z,
                                               const ushort* __restrict__ Wt2l,
                                               float* __restrict__ hnext,
                                               float* __restrict__ bnrep_l) {
    constexpr int NT = DOUT / 16;
    constexpr int W = 2 * DOUT;
    __shared__ float pl[4][W];
    int tid = threadIdx.x;
    int widx = tid >> 6, lane = tid & 63;
    int wid = blockIdx.x * 4 + widx;
    int mtile = wid / NT;
    int nt = wid - mtile * NT;
    bool active = (mtile < kN / 16);
    int m0 = mtile * 16;
    int n0 = nt * 16;

    int row = lane & 15;
    int k0  = (lane >> 4) * 8;

    for (int j = tid; j < 4 * W; j += 256) (&pl[0][0])[j] = 0.f;

    f32x4 acc = {0.f, 0.f, 0.f, 0.f};
    if (active) {
        const ushort* za = z + (size_t)(m0 + row) * 256 + k0;
        const ushort* wb = Wt2l + (size_t)(n0 + row) * 256 + k0;
#pragma unroll
        for (int ks = 0; ks < 8; ++ks) {
            bf16x8 a = *reinterpret_cast<const bf16x8*>(za + ks * 32);
            bf16x8 b = *reinterpret_cast<const bf16x8*>(wb + ks * 32);
            acc = __builtin_amdgcn_mfma_f32_16x16x32_bf16(a, b, acc, 0, 0, 0);
        }
        int col = lane & 15;
        int r0  = (lane >> 4) * 4;
#pragma unroll
        for (int r = 0; r < 4; ++r)
            hnext[(size_t)(m0 + r0 + r) * DOUT + n0 + col] = acc[r];
    }

    float s0 = 0.f, q0 = 0.f;
#pragma unroll
    for (int r = 0; r < 4; ++r) { s0 += acc[r]; q0 += acc[r] * acc[r]; }
    s0 += __shfl_xor(s0, 16); s0 += __shfl_xor(s0, 32);
    q0 += __shfl_xor(q0, 16); q0 += __shfl_xor(q0, 32);
    __syncthreads();
    if (lane < 16) {
        pl[widx][n0 + lane]        = s0;
        pl[widx][DOUT + n0 + lane] = q0;
    }
    __syncthreads();
    if (tid < W) {
        float t = pl[0][tid] + pl[1][tid] + pl[2][tid] + pl[3][tid];
        atomicAdd(&bnrep_l[(blockIdx.x & (kRep - 1)) * 128 + tid], t);
    }
}

// BN apply (layers 0,1) fused with NEXT layer's es/ed; sums kRep BN replicas.
__global__ void __launch_bounds__(256) k_bn_apply_att(const float* __restrict__ hnext,
                                                      const float* __restrict__ bnrep_l,
                                                      const float* __restrict__ g,
                                                      const float* __restrict__ be,
                                                      const float* __restrict__ ahat_next,
                                                      ushort* __restrict__ hcur,
                                                      float* __restrict__ es,
                                                      float* __restrict__ ed) {
    int node = blockIdx.x * 4 + (threadIdx.x >> 6);
    int lane = threadIdx.x & 63;
    float bs = 0.f, bq = 0.f;
#pragma unroll
    for (int r = 0; r < kRep; ++r) {
        bs += bnrep_l[r * 128 + lane];
        bq += bnrep_l[r * 128 + 64 + lane];
    }
    float mu = bs * (1.f / kN);
    float var = bq * (1.f / kN) - mu * mu;
    float v = g[lane] * (hnext[(size_t)node * 64 + lane] - mu) * rsqrtf(var + 1e-5f) + be[lane];
    v = fmaxf(v, 0.f);
    hcur[(size_t)node * 64 + lane] = f2b(v);

    float ps[4], pd[4];
#pragma unroll
    for (int hh = 0; hh < 4; ++hh) {
        ps[hh] = v * ahat_next[hh * 64 + lane];
        pd[hh] = v * ahat_next[256 + hh * 64 + lane];
    }
#pragma unroll
    for (int off = 1; off < 64; off <<= 1) {
#pragma unroll
        for (int hh = 0; hh < 4; ++hh) {
            ps[hh] += __shfl_xor(ps[hh], off);
            pd[hh] += __shfl_xor(pd[hh], off);
        }
    }
    if (lane == 0) {
        ((float4*)es)[node] = make_float4(ps[0], ps[1], ps[2], ps[3]);
        ((float4*)ed)[node] = make_float4(pd[0], pd[1], pd[2], pd[3]);
    }
}

// final BN apply (layer 2) fused with pooling partials; sums kRep BN replicas.
__global__ void __launch_bounds__(256) k_bn_apply32_pool(const float* __restrict__ hnext,
                                                         const float* __restrict__ bnrep_l,
                                                         const float* __restrict__ g,
                                                         const float* __restrict__ be,
                                                         const int* __restrict__ batch,
                                                         float* __restrict__ out_h,
                                                         float* __restrict__ gsum,
                                                         unsigned* __restrict__ gmaxe) {
    int tid = threadIdx.x;
    int i = blockIdx.x * 256 + tid;   // exactly kN*32 threads
    int n = i >> 5, c = i & 31;
    float bs = 0.f, bq = 0.f;
#pragma unroll
    for (int r = 0; r < kRep; ++r) {
        bs += bnrep_l[r * 128 + c];
        bq += bnrep_l[r * 128 + 32 + c];
    }
    float mu = bs * (1.f / kN);
    float var = bq * (1.f / kN) - mu * mu;
    float v = g[c] * (hnext[i] - mu) * rsqrtf(var + 1e-5f) + be[c];
    out_h[i] = v;

    __shared__ float ls[256];
    ls[tid] = v;
    __syncthreads();
    int nb0 = blockIdx.x * 8;
    int gfirst = batch[nb0], glast = batch[nb0 + 7];
    if (gfirst == glast) {
        if (tid < 32) {
            float s = 0.f;
            unsigned me = 0u;
#pragma unroll
            for (int r = 0; r < 8; ++r) {
                float vv = ls[r * 32 + tid];
                s += vv;
                unsigned e = enc_f(vv);
                me = (e > me) ? e : me;
            }
            atomicAdd(&gsum[gfirst * 32 + tid], s);
            atomicMax(&gmaxe[gfirst * 32 + tid], me);
        }
    } else {
        int gg = batch[n];
        atomicAdd(&gsum[gg * 32 + c], v);
        atomicMax(&gmaxe[gg * 32 + c], enc_f(v));
    }
}

// finalize pooling + both MLP heads (single block)
__global__ void __launch_bounds__(256) k_finish(const float* __restrict__ gsum,
                                                const unsigned* __restrict__ gmaxe,
                                                const int* __restrict__ batch,
                                                const float* __restrict__ ew1,
                                                const float* __restrict__ eb1,
                                                const float* __restrict__ ew2,
                                                const float* __restrict__ eb2,
                                                const float* __restrict__ mw1,
                                                const float* __restrict__ mb1,
                                                const float* __restrict__ mw2,
                                                const float* __restrict__ mb2,
                                                float* __restrict__ out_gemb,
                                                float* __restrict__ out_eth,
                                                float* __restrict__ out_man) {
    __shared__ int bound[kG + 1];
    __shared__ float ge[kG * 32];
    int tid = threadIdx.x;
    if (tid <= kG) {
        int lo = 0, hi = kN;
        while (lo < hi) { int mid = (lo + hi) >> 1; if (batch[mid] < tid) lo = mid + 1; else hi = mid; }
        bound[tid] = lo;
    }
    __syncthreads();
    for (int j = tid; j < kG * 32; j += 256) {
        int gg = j >> 5;
        int cnt = bound[gg + 1] - bound[gg];
        float sum = gsum[j];
        float mx = (cnt > 0) ? dec_f(gmaxe[j]) : 0.f;
        float mean = sum / fmaxf((float)cnt, 1.f);
        float e = (mean + mx + sum) * (1.f / 3.f);
        ge[j] = e;
        out_gemb[j] = e;
    }
    __syncthreads();
    if (tid < kG) {
        const float* row = &ge[tid * 32];
        float acc_e = eb2[0], acc_m = mb2[0];
#pragma unroll 4
        for (int j = 0; j < 16; ++j) {
            float he = eb1[j], hm = mb1[j];
            for (int k = 0; k < 32; ++k) {
                float v = row[k];
                he += v * ew1[k * 16 + j];
                hm += v * mw1[k * 16 + j];
            }
            acc_e += fmaxf(he, 0.f) * ew2[j];
            acc_m += fmaxf(hm, 0.f) * mw2[j];
        }
        out_eth[tid] = 1.f / (1.f + expf(-acc_e));
        out_man[tid] = 1.f / (1.f + expf(-acc_m));
    }
}

extern "C" void kernel_launch(void* const* d_in, const int* in_sizes, int n_in,
                              void* d_out, int out_size, void* d_ws, size_t ws_size,
                              hipStream_t stream) {
    const float* x     = (const float*)d_in[0];
    const int*   ei    = (const int*)d_in[1];
    const int*   batch = (const int*)d_in[2];
    const float* enc_w = (const float*)d_in[3];
    const float* enc_b = (const float*)d_in[4];

    float* ws = (float*)d_ws;
    ushort*   hcur  = (ushort*)(ws + OFF_HCUR);
    float*    hnext = ws + OFF_HNEXT;
    ushort*   z     = (ushort*)(ws + OFF_Z);
    float*    es    = ws + OFF_ES;
    float*    ed    = ws + OFF_ED;
    int*      rowptr= (int*)(ws + OFF_ROWPTR);
    ushort*   srcc  = (ushort*)(ws + OFF_SRC);
    ushort*   Wt2   = (ushort*)(ws + OFF_WT2);
    float*    ahat  = ws + OFF_AHAT;
    int*      spart = (int*)(ws + OFF_SPART);
    int*      cursor= (int*)(ws + OFF_CURSOR);
    float*    bnrep = ws + OFF_BNREP;
    float*    gsum  = ws + OFF_GPOOL;
    unsigned* gmaxe = (unsigned*)(ws + OFF_GPOOL + 1600);

    float* out      = (float*)d_out;
    float* out_h    = out;                 // N*32
    float* out_gemb = out + 1600000;       // G*32
    float* out_eth  = out + 1601600;       // G
    float* out_man  = out + 1601650;       // G

    // ---- single zero-init: cursor + bnrep + gpool (contiguous) ----
    hipMemsetAsync(ws + OFF_CURSOR, 0, (kZeroEnd - OFF_CURSOR) * sizeof(float), stream);

    // ---- weight prep + dst histogram (fused) ----
    k_histprep<<<kPrepBlocks + kHistBlocks, 256, 0, stream>>>(
        ei, cursor,
        (const float*)d_in[5], (const float*)d_in[11], (const float*)d_in[17],
        (const float*)d_in[6], (const float*)d_in[12], (const float*)d_in[18],
        (const float*)d_in[7], (const float*)d_in[13], (const float*)d_in[19],
        ahat, Wt2);

    // ---- scan ----
    k_scan_local<<<kScanBlocks, 1024, 0, stream>>>(cursor, rowptr, spart);
    k_scan_part<<<1, 64, 0, stream>>>(spart);
    k_scan_add<<<kScanBlocks, 1024, 0, stream>>>(cursor, rowptr, spart);

    // ---- scatter (XCD-binned) + self-loops + encoder/layer-0 att (fused) ----
    k_scatter_enc<<<kEncBlocks + kSctBlocks + kLoopBlocks, 256, 0, stream>>>(
        ei, cursor, srcc, rowptr, x, enc_w, enc_b, ahat, hcur, es, ed);

    for (int l = 0; l < 3; ++l) {
        const float* gam = (const float*)d_in[9 + 6 * l];
        const float* bet = (const float*)d_in[10 + 6 * l];
        const ushort* Wt2l = Wt2 + l * 16384;
        float* bnrep_l = bnrep + l * kRep * 128;

        k_gat<<<kN / 4, 256, 0, stream>>>(rowptr, srcc, es, ed, hcur, z);

        if (l < 2) {
            k_zgemm<64><<<3125, 256, 0, stream>>>(z, Wt2l, hnext, bnrep_l);
            k_bn_apply_att<<<kN / 4, 256, 0, stream>>>(hnext, bnrep_l, gam, bet,
                                                       ahat + (l + 1) * 512, hcur, es, ed);
        } else {
            k_zgemm<32><<<1563, 256, 0, stream>>>(z, Wt2l, hnext, bnrep_l);
            k_bn_apply32_pool<<<kN * 32 / 256, 256, 0, stream>>>(hnext, bnrep_l, gam, bet,
                                                                 batch, out_h, gsum, gmaxe);
        }
    }

    k_finish<<<1, 256, 0, stream>>>(gsum, gmaxe, batch,
                                    (const float*)d_in[23], (const float*)d_in[24],
                                    (const float*)d_in[25], (const float*)d_in[26],
                                    (const float*)d_in[27], (const float*)d_in[28],
                                    (const float*)d_in[29], (const float*)d_in[30],
                                    out_gemb, out_eth, out_man);
}